// Round 5
// baseline (351.648 us; speedup 1.0000x reference)
//
#include <hip/hip_runtime.h>
#include <math.h>

typedef unsigned int u32;
typedef unsigned long long u64;
typedef long long i64;

#define BINS 256
#define TBITS 0x40000000u   /* bit pattern of 2.0f : fixed compaction threshold  */
#define TBUCKET 512u        /* TBITS >> 21 : first coarse bucket of candidates   */
#define SLOT 2048           /* per-block private candidate slot (mean ~745)      */
#define NBLK 512            /* blocks per channel for full passes                */

// ---------------- helpers ----------------

// Bit-exact replica of the float32 numpy pipeline:
//   idx = trunc(min(|x|/mv, 1.0f) * 255.0f)   (*8 and /8 are exact pow2 ops)
__device__ __forceinline__ int bin_index_f32(float xv, float mv) {
    float r = __fdiv_rn(fabsf(xv), mv);
    r = fminf(r, 1.0f);
    return (int)__fmul_rn(r, 255.0f);
}

// Parallel rank-select over h[0..nb) for `target` (256 threads, nb in {1024,2048}).
// One thread finds the bucket; res[0]=bucket, res[1]=target-cum_excl(bucket).
__device__ void block_select(const u32* __restrict__ h, int nb, u32 target,
                             u32* ssum, u32* res) {
    const int t = threadIdx.x;
    const int per = nb >> 8;
    u32 loc[8];
    u32 s = 0;
    const int base = t * per;
    for (int j = 0; j < per; ++j) { loc[j] = h[base + j]; s += loc[j]; }
    ssum[t] = s;
    __syncthreads();
    for (int off = 1; off < 256; off <<= 1) {
        u32 add = (t >= off) ? ssum[t - off] : 0;
        __syncthreads();
        ssum[t] += add;
        __syncthreads();
    }
    u32 cum = ssum[t] - s;
    for (int j = 0; j < per; ++j) {
        u32 cnt = loc[j];
        if (target >= cum && target < cum + cnt) { res[0] = (u32)(base + j); res[1] = target - cum; }
        cum += cnt;
    }
    __syncthreads();
}

// ---------------- pass 1: 1024-bin radix hist + deterministic-slot compaction ----------------

__global__ __launch_bounds__(256) void k_pass1(const float* __restrict__ x, u32* __restrict__ histA,
                                               u32* __restrict__ cand, u32* __restrict__ oflow,
                                               i64 nper, int do_cand) {
    __shared__ u32 lh[8][1025];
    __shared__ u32 lbuf[SLOT];
    __shared__ u32 lcnt;
    const int c = blockIdx.y;
    for (int i = threadIdx.x; i < 8 * 1025; i += 256) (&lh[0][0])[i] = 0;
    if (threadIdx.x == 0) lcnt = 0;
    __syncthreads();
    const float* xc = x + (i64)c * nper;
    const i64 nv2 = nper >> 3;
    const int copy = threadIdx.x & 7;
    const float4* xv = (const float4*)xc;
    for (i64 i = (i64)blockIdx.x * 256 + threadIdx.x; i < nv2; i += (i64)gridDim.x * 256) {
        float4 a = xv[2 * i], b = xv[2 * i + 1];
        u32 bb[8];
        bb[0] = __float_as_uint(fabsf(a.x)); bb[1] = __float_as_uint(fabsf(a.y));
        bb[2] = __float_as_uint(fabsf(a.z)); bb[3] = __float_as_uint(fabsf(a.w));
        bb[4] = __float_as_uint(fabsf(b.x)); bb[5] = __float_as_uint(fabsf(b.y));
        bb[6] = __float_as_uint(fabsf(b.z)); bb[7] = __float_as_uint(fabsf(b.w));
#pragma unroll
        for (int k = 0; k < 8; ++k) {
            atomicAdd(&lh[copy][bb[k] >> 21], 1u);
            if (bb[k] >= TBITS) {
                u32 p = atomicAdd(&lcnt, 1u);
                if (p < SLOT) lbuf[p] = bb[k];
            }
        }
    }
    const int rem = (int)(nper & 7);
    if (blockIdx.x == 0 && threadIdx.x < rem) {
        u32 bb = __float_as_uint(fabsf(xc[nv2 * 8 + threadIdx.x]));
        atomicAdd(&lh[copy][bb >> 21], 1u);
        if (bb >= TBITS) {
            u32 p = atomicAdd(&lcnt, 1u);
            if (p < SLOT) lbuf[p] = bb;
        }
    }
    __syncthreads();
    for (int i = threadIdx.x; i < 1024; i += 256) {
        u32 s = 0;
#pragma unroll
        for (int k = 0; k < 8; ++k) s += lh[k][i];
        if (s) atomicAdd(&histA[c * 1024 + i], s);
    }
    if (threadIdx.x == 0 && lcnt > SLOT) {
        atomicExch(&oflow[c], 1u);   // idempotent OR: deterministic regardless of order
        lcnt = SLOT;
    }
    __syncthreads();
    if (do_cand) {
        const u32 cnt = lcnt;
        u32* slot = cand + ((i64)c * gridDim.x + blockIdx.x) * SLOT;
        for (u32 j = threadIdx.x; j < SLOT; j += 256)
            slot[j] = (j < cnt) ? lbuf[j] : 0u;   // pad = 0x0, below all candidates
    }
}

// ---------------- candidate select stage 1 (bits 31..21) over padded fixed region ----------------

__global__ __launch_bounds__(256) void k_csel_hist1(const u32* __restrict__ cand,
                                                    u32* __restrict__ ch1024, i64 ntot) {
    __shared__ u32 lh[8][1025];
    const int c = blockIdx.y;
    for (int i = threadIdx.x; i < 8 * 1025; i += 256) (&lh[0][0])[i] = 0;
    __syncthreads();
    const int copy = threadIdx.x & 7;
    const uint4* cd = (const uint4*)(cand + (i64)c * ntot);
    const i64 nv4 = ntot >> 2;
    for (i64 i = (i64)blockIdx.x * 256 + threadIdx.x; i < nv4; i += (i64)gridDim.x * 256) {
        uint4 v = cd[i];
        atomicAdd(&lh[copy][v.x >> 21], 1u);
        atomicAdd(&lh[copy][v.y >> 21], 1u);
        atomicAdd(&lh[copy][v.z >> 21], 1u);
        atomicAdd(&lh[copy][v.w >> 21], 1u);
    }
    __syncthreads();
    for (int i = threadIdx.x; i < 1024; i += 256) {
        u32 s = 0;
#pragma unroll
        for (int k = 0; k < 8; ++k) s += lh[k][i];
        if (s) atomicAdd(&ch1024[c * 1024 + i], s);
    }
}

__global__ __launch_bounds__(256) void k_csel_pick1(const u32* __restrict__ ch1024,
                                                    const u32* __restrict__ oflow,
                                                    u32* __restrict__ flag, u32* __restrict__ csel1, u32 t0) {
    __shared__ u32 ssum[256];
    __shared__ u32 pr[4];
    const int c = blockIdx.x;
    if (threadIdx.x < 4) pr[threadIdx.x] = 0;
    __syncthreads();
    block_select(ch1024 + c * 1024, 1024, t0, ssum, &pr[0]);
    block_select(ch1024 + c * 1024, 1024, t0 + 1, ssum, &pr[2]);
    if (threadIdx.x == 0) {
        // valid only if both ranks land in the candidate bucket range (>= TBUCKET)
        u32 bad = (oflow[c] != 0) || (pr[0] < TBUCKET) || (pr[2] < TBUCKET);
        flag[c] = bad;
        csel1[c * 4 + 0] = pr[0]; csel1[c * 4 + 1] = pr[1];
        csel1[c * 4 + 2] = pr[2]; csel1[c * 4 + 3] = pr[3];
    }
}

// ---------------- candidate select stage 2 (bits 20..10) ----------------

__global__ __launch_bounds__(256) void k_csel_hist2(const u32* __restrict__ cand, const u32* __restrict__ flag,
                                                    const u32* __restrict__ csel1,
                                                    u32* __restrict__ h2a, u32* __restrict__ h2b, i64 ntot) {
    const int c = blockIdx.y;
    if (flag[c]) return;
    __shared__ u32 la[2048], lb[2048];
    for (int i = threadIdx.x; i < 2048; i += 256) { la[i] = 0; lb[i] = 0; }
    __syncthreads();
    const u32 a0 = csel1[c * 4 + 0], a1 = csel1[c * 4 + 2];
    const u32* cd = cand + (i64)c * ntot;
    for (i64 i = (i64)blockIdx.x * 256 + threadIdx.x; i < ntot; i += (i64)gridDim.x * 256) {
        u32 v = cd[i], t = v >> 21;
        if (t == a0) atomicAdd(&la[(v >> 10) & 2047], 1u);
        if (t == a1) atomicAdd(&lb[(v >> 10) & 2047], 1u);
    }
    __syncthreads();
    for (int i = threadIdx.x; i < 2048; i += 256) {
        if (la[i]) atomicAdd(&h2a[c * 2048 + i], la[i]);
        if (lb[i]) atomicAdd(&h2b[c * 2048 + i], lb[i]);
    }
}

__global__ __launch_bounds__(256) void k_csel_pick2(const u32* __restrict__ h2a, const u32* __restrict__ h2b,
                                                    const u32* __restrict__ flag, const u32* __restrict__ csel1,
                                                    u32* __restrict__ csel2) {
    __shared__ u32 ssum[256];
    __shared__ u32 pr[4];
    const int c = blockIdx.x;
    if (flag[c]) return;
    if (threadIdx.x < 4) pr[threadIdx.x] = 0;
    __syncthreads();
    block_select(h2a + c * 2048, 2048, csel1[c * 4 + 1], ssum, &pr[0]);
    block_select(h2b + c * 2048, 2048, csel1[c * 4 + 3], ssum, &pr[2]);
    if (threadIdx.x == 0) {
        csel2[c * 4 + 0] = (csel1[c * 4 + 0] << 11) | pr[0]; csel2[c * 4 + 1] = pr[1];
        csel2[c * 4 + 2] = (csel1[c * 4 + 2] << 11) | pr[2]; csel2[c * 4 + 3] = pr[3];
    }
}

// ---------------- candidate select stage 3 (bits 9..0) + numpy f32 lerp ----------------

__global__ __launch_bounds__(256) void k_csel_hist3(const u32* __restrict__ cand, const u32* __restrict__ flag,
                                                    const u32* __restrict__ csel2,
                                                    u32* __restrict__ h3a, u32* __restrict__ h3b, i64 ntot) {
    const int c = blockIdx.y;
    if (flag[c]) return;
    __shared__ u32 la[1024], lb[1024];
    for (int i = threadIdx.x; i < 1024; i += 256) { la[i] = 0; lb[i] = 0; }
    __syncthreads();
    const u32 A0 = csel2[c * 4 + 0], A1 = csel2[c * 4 + 2];
    const u32* cd = cand + (i64)c * ntot;
    for (i64 i = (i64)blockIdx.x * 256 + threadIdx.x; i < ntot; i += (i64)gridDim.x * 256) {
        u32 v = cd[i], t = v >> 10;
        if (t == A0) atomicAdd(&la[v & 1023], 1u);
        if (t == A1) atomicAdd(&lb[v & 1023], 1u);
    }
    __syncthreads();
    for (int i = threadIdx.x; i < 1024; i += 256) {
        if (la[i]) atomicAdd(&h3a[c * 1024 + i], la[i]);
        if (lb[i]) atomicAdd(&h3b[c * 1024 + i], lb[i]);
    }
}

__global__ __launch_bounds__(256) void k_csel_pick3(const u32* __restrict__ h3a, const u32* __restrict__ h3b,
                                                    const u32* __restrict__ flag, const u32* __restrict__ csel2,
                                                    float* __restrict__ mv, double gamma) {
    __shared__ u32 ssum[256];
    __shared__ u32 pr[4];
    const int c = blockIdx.x;
    if (flag[c]) return;
    if (threadIdx.x < 4) pr[threadIdx.x] = 0;
    __syncthreads();
    block_select(h3a + c * 1024, 1024, csel2[c * 4 + 1], ssum, &pr[0]);
    block_select(h3b + c * 1024, 1024, csel2[c * 4 + 3], ssum, &pr[2]);
    if (threadIdx.x == 0) {
        float v0 = __uint_as_float((csel2[c * 4 + 0] << 10) | pr[0]);
        float v1 = __uint_as_float((csel2[c * 4 + 2] << 10) | pr[2]);
        float dba = __fsub_rn(v1, v0);
        float q;
        if (gamma >= 0.5) q = __fsub_rn(v1, __fmul_rn(dba, (float)(1.0 - gamma)));
        else              q = __fadd_rn(v0, __fmul_rn(dba, (float)gamma));
        mv[c] = fmaxf(q, 1e-8f);
    }
}

__global__ void k_flag_force(u32* __restrict__ flag, int C) {
    if (threadIdx.x < C) flag[threadIdx.x] = 1u;
}

// ---------------- fallback chain (exact round-3 path; flag-gated early-exit) ----------------

__global__ __launch_bounds__(256) void k_scan_l1(const u32* __restrict__ histA, const u32* __restrict__ flag,
                                                 u32* __restrict__ sel1, u32 k0) {
    __shared__ u32 ssum[256];
    __shared__ u32 pr[4];
    const int c = blockIdx.x;
    if (!flag[c]) return;
    if (threadIdx.x < 4) pr[threadIdx.x] = 0;
    __syncthreads();
    block_select(histA + c * 1024, 1024, k0, ssum, &pr[0]);
    block_select(histA + c * 1024, 1024, k0 + 1, ssum, &pr[2]);
    if (threadIdx.x == 0) {
        sel1[c * 4 + 0] = pr[0]; sel1[c * 4 + 1] = pr[1];
        sel1[c * 4 + 2] = pr[2]; sel1[c * 4 + 3] = pr[3];
    }
}

__global__ __launch_bounds__(256) void k_hist_l2(const float* __restrict__ x, const u32* __restrict__ flag,
                                                 const u32* __restrict__ sel1,
                                                 u32* __restrict__ hB0, u32* __restrict__ hB1, i64 nper) {
    const int c = blockIdx.y;
    if (!flag[c]) return;
    __shared__ u32 lh0[2048], lh1[2048];
    const u32 p0 = sel1[c * 4 + 0], p1 = sel1[c * 4 + 2];
    const bool two = (p1 != p0);
    for (int i = threadIdx.x; i < 2048; i += 256) { lh0[i] = 0; lh1[i] = 0; }
    __syncthreads();
    const float* xc = x + (i64)c * nper;
    const i64 nv = nper >> 2;
    const float4* xv = (const float4*)xc;
    for (i64 i = (i64)blockIdx.x * 256 + threadIdx.x; i < nv; i += (i64)gridDim.x * 256) {
        float4 v = xv[i];
        u32 b;
        b = __float_as_uint(fabsf(v.x));
        if ((b >> 21) == p0) atomicAdd(&lh0[(b >> 10) & 2047], 1u);
        else if (two && (b >> 21) == p1) atomicAdd(&lh1[(b >> 10) & 2047], 1u);
        b = __float_as_uint(fabsf(v.y));
        if ((b >> 21) == p0) atomicAdd(&lh0[(b >> 10) & 2047], 1u);
        else if (two && (b >> 21) == p1) atomicAdd(&lh1[(b >> 10) & 2047], 1u);
        b = __float_as_uint(fabsf(v.z));
        if ((b >> 21) == p0) atomicAdd(&lh0[(b >> 10) & 2047], 1u);
        else if (two && (b >> 21) == p1) atomicAdd(&lh1[(b >> 10) & 2047], 1u);
        b = __float_as_uint(fabsf(v.w));
        if ((b >> 21) == p0) atomicAdd(&lh0[(b >> 10) & 2047], 1u);
        else if (two && (b >> 21) == p1) atomicAdd(&lh1[(b >> 10) & 2047], 1u);
    }
    if (blockIdx.x == 0 && threadIdx.x < (int)(nper & 3)) {
        u32 b = __float_as_uint(fabsf(xc[nv * 4 + threadIdx.x]));
        if ((b >> 21) == p0) atomicAdd(&lh0[(b >> 10) & 2047], 1u);
        else if (two && (b >> 21) == p1) atomicAdd(&lh1[(b >> 10) & 2047], 1u);
    }
    __syncthreads();
    for (int i = threadIdx.x; i < 2048; i += 256) {
        if (lh0[i]) atomicAdd(&hB0[c * 2048 + i], lh0[i]);
        if (two && lh1[i]) atomicAdd(&hB1[c * 2048 + i], lh1[i]);
    }
}

__global__ __launch_bounds__(256) void k_scan_l2(const u32* __restrict__ hB0, const u32* __restrict__ hB1,
                                                 const u32* __restrict__ flag,
                                                 const u32* __restrict__ sel1, u32* __restrict__ sel2) {
    __shared__ u32 ssum[256];
    __shared__ u32 pr[4];
    const int c = blockIdx.x;
    if (!flag[c]) return;
    if (threadIdx.x < 4) pr[threadIdx.x] = 0;
    __syncthreads();
    const u32 p0 = sel1[c * 4 + 0], p1 = sel1[c * 4 + 2];
    const u32* h0 = hB0 + c * 2048;
    const u32* h1 = (p1 == p0) ? h0 : (hB1 + c * 2048);
    block_select(h0, 2048, sel1[c * 4 + 1], ssum, &pr[0]);
    block_select(h1, 2048, sel1[c * 4 + 3], ssum, &pr[2]);
    if (threadIdx.x == 0) {
        sel2[c * 4 + 0] = (p0 << 11) | pr[0]; sel2[c * 4 + 1] = pr[1];
        sel2[c * 4 + 2] = (p1 << 11) | pr[2]; sel2[c * 4 + 3] = pr[3];
    }
}

__global__ __launch_bounds__(256) void k_hist_l3(const float* __restrict__ x, const u32* __restrict__ flag,
                                                 const u32* __restrict__ sel2,
                                                 u32* __restrict__ hC0, u32* __restrict__ hC1, i64 nper) {
    const int c = blockIdx.y;
    if (!flag[c]) return;
    __shared__ u32 lh0[1024], lh1[1024];
    const u32 p0 = sel2[c * 4 + 0], p1 = sel2[c * 4 + 2];
    const bool two = (p1 != p0);
    for (int i = threadIdx.x; i < 1024; i += 256) { lh0[i] = 0; lh1[i] = 0; }
    __syncthreads();
    const float* xc = x + (i64)c * nper;
    const i64 nv = nper >> 2;
    const float4* xv = (const float4*)xc;
    for (i64 i = (i64)blockIdx.x * 256 + threadIdx.x; i < nv; i += (i64)gridDim.x * 256) {
        float4 v = xv[i];
        u32 b;
        b = __float_as_uint(fabsf(v.x));
        if ((b >> 10) == p0) atomicAdd(&lh0[b & 1023], 1u);
        else if (two && (b >> 10) == p1) atomicAdd(&lh1[b & 1023], 1u);
        b = __float_as_uint(fabsf(v.y));
        if ((b >> 10) == p0) atomicAdd(&lh0[b & 1023], 1u);
        else if (two && (b >> 10) == p1) atomicAdd(&lh1[b & 1023], 1u);
        b = __float_as_uint(fabsf(v.z));
        if ((b >> 10) == p0) atomicAdd(&lh0[b & 1023], 1u);
        else if (two && (b >> 10) == p1) atomicAdd(&lh1[b & 1023], 1u);
        b = __float_as_uint(fabsf(v.w));
        if ((b >> 10) == p0) atomicAdd(&lh0[b & 1023], 1u);
        else if (two && (b >> 10) == p1) atomicAdd(&lh1[b & 1023], 1u);
    }
    if (blockIdx.x == 0 && threadIdx.x < (int)(nper & 3)) {
        u32 b = __float_as_uint(fabsf(xc[nv * 4 + threadIdx.x]));
        if ((b >> 10) == p0) atomicAdd(&lh0[b & 1023], 1u);
        else if (two && (b >> 10) == p1) atomicAdd(&lh1[b & 1023], 1u);
    }
    __syncthreads();
    for (int i = threadIdx.x; i < 1024; i += 256) {
        if (lh0[i]) atomicAdd(&hC0[c * 1024 + i], lh0[i]);
        if (two && lh1[i]) atomicAdd(&hC1[c * 1024 + i], lh1[i]);
    }
}

__global__ __launch_bounds__(256) void k_finalize(const u32* __restrict__ hC0, const u32* __restrict__ hC1,
                                                  const u32* __restrict__ flag,
                                                  const u32* __restrict__ sel2, float* __restrict__ mv,
                                                  double gamma) {
    __shared__ u32 ssum[256];
    __shared__ u32 pr[4];
    const int c = blockIdx.x;
    if (!flag[c]) return;
    if (threadIdx.x < 4) pr[threadIdx.x] = 0;
    __syncthreads();
    const u32 p0 = sel2[c * 4 + 0], p1 = sel2[c * 4 + 2];
    const u32* h0 = hC0 + c * 1024;
    const u32* h1 = (p1 == p0) ? h0 : (hC1 + c * 1024);
    block_select(h0, 1024, sel2[c * 4 + 1], ssum, &pr[0]);
    block_select(h1, 1024, sel2[c * 4 + 3], ssum, &pr[2]);
    if (threadIdx.x == 0) {
        float v0 = __uint_as_float((p0 << 10) | pr[0]);
        float v1 = __uint_as_float((p1 << 10) | pr[2]);
        float dba = __fsub_rn(v1, v0);
        float q;
        if (gamma >= 0.5) q = __fsub_rn(v1, __fmul_rn(dba, (float)(1.0 - gamma)));
        else              q = __fadd_rn(v0, __fmul_rn(dba, (float)gamma));
        mv[c] = fmaxf(q, 1e-8f);
    }
}

// ---------------- 256-bin index histogram ----------------

__global__ __launch_bounds__(256) void k_hist_idx(const float* __restrict__ x, const float* __restrict__ mv,
                                                  u32* __restrict__ h256, i64 nper) {
    __shared__ u32 lh[8][257];
    const int c = blockIdx.y;
    const float m = mv[c];
    for (int i = threadIdx.x; i < 8 * 257; i += 256) (&lh[0][0])[i] = 0;
    __syncthreads();
    const float* xc = x + (i64)c * nper;
    const i64 nv2 = nper >> 3;
    const int copy = threadIdx.x & 7;
    const float4* xv = (const float4*)xc;
    for (i64 i = (i64)blockIdx.x * 256 + threadIdx.x; i < nv2; i += (i64)gridDim.x * 256) {
        float4 a = xv[2 * i], b = xv[2 * i + 1];
        atomicAdd(&lh[copy][bin_index_f32(a.x, m)], 1u);
        atomicAdd(&lh[copy][bin_index_f32(a.y, m)], 1u);
        atomicAdd(&lh[copy][bin_index_f32(a.z, m)], 1u);
        atomicAdd(&lh[copy][bin_index_f32(a.w, m)], 1u);
        atomicAdd(&lh[copy][bin_index_f32(b.x, m)], 1u);
        atomicAdd(&lh[copy][bin_index_f32(b.y, m)], 1u);
        atomicAdd(&lh[copy][bin_index_f32(b.z, m)], 1u);
        atomicAdd(&lh[copy][bin_index_f32(b.w, m)], 1u);
    }
    if (blockIdx.x == 0 && threadIdx.x < (int)(nper & 7)) {
        atomicAdd(&lh[copy][bin_index_f32(xc[nv2 * 8 + threadIdx.x], m)], 1u);
    }
    __syncthreads();
    for (int i = threadIdx.x; i < BINS; i += 256) {
        u32 s = 0;
#pragma unroll
        for (int k = 0; k < 8; ++k) s += lh[k][i];
        if (s) atomicAdd(&h256[c * BINS + i], s);
    }
}

// ---------------- output: fused mask-table (per-block LDS) + out = x * mask[idx] ----------------

__global__ __launch_bounds__(256) void k_output(const float* __restrict__ x, const float* __restrict__ mv,
                                                const float* __restrict__ hist_in, const float* __restrict__ logp_ref,
                                                const u32* __restrict__ h256, float* __restrict__ out, i64 nper) {
    __shared__ double smv_s[BINS];
    __shared__ double maskl[BINS];
    __shared__ double stot;
    const int c = blockIdx.y;
    const int b = threadIdx.x;
    // EMA with separately-rounded f32 ops, matching numpy ufunc-by-ufunc rounding
    float h = hist_in[c * BINS + b];
    float nn = (float)h256[c * BINS + b];
    float t = __fadd_rn(__fmul_rn(0.98f, h), __fmul_rn(0.02f, nn));
    float smf = __fadd_rn(t, 1e-8f);
    double sm = (double)smf;
    smv_s[b] = sm;
    __syncthreads();
    if (b < 64) {
        double s = smv_s[b] + smv_s[b + 64] + smv_s[b + 128] + smv_s[b + 192];
        for (int o = 32; o; o >>= 1) s += __shfl_down(s, o);
        if (b == 0) stot = s;
    }
    __syncthreads();
    double Lam = (double)logp_ref[c * BINS + b] - log(sm / stot);
    maskl[b] = 1.0 / (1.0 + exp(Lam + 2.0));   // sigmoid(-(Lam - THRESH)), THRESH = -2
    __syncthreads();

    const float m = mv[c];
    const float* xc = x + (i64)c * nper;
    float* oc = out + (i64)c * nper;
    const i64 nv2 = nper >> 3;
    const float4* xv = (const float4*)xc;
    float4* ov = (float4*)oc;
    for (i64 i = (i64)blockIdx.x * 256 + threadIdx.x; i < nv2; i += (i64)gridDim.x * 256) {
        float4 a = xv[2 * i], bb = xv[2 * i + 1];
        float4 oa, ob;
        oa.x = (float)((double)a.x * maskl[bin_index_f32(a.x, m)]);
        oa.y = (float)((double)a.y * maskl[bin_index_f32(a.y, m)]);
        oa.z = (float)((double)a.z * maskl[bin_index_f32(a.z, m)]);
        oa.w = (float)((double)a.w * maskl[bin_index_f32(a.w, m)]);
        ob.x = (float)((double)bb.x * maskl[bin_index_f32(bb.x, m)]);
        ob.y = (float)((double)bb.y * maskl[bin_index_f32(bb.y, m)]);
        ob.z = (float)((double)bb.z * maskl[bin_index_f32(bb.z, m)]);
        ob.w = (float)((double)bb.w * maskl[bin_index_f32(bb.w, m)]);
        ov[2 * i] = oa;
        ov[2 * i + 1] = ob;
    }
    if (blockIdx.x == 0 && threadIdx.x < (int)(nper & 7)) {
        i64 i = nv2 * 8 + threadIdx.x;
        float v = xc[i];
        oc[i] = (float)((double)v * maskl[bin_index_f32(v, m)]);
    }
}

// ---------------- launch ----------------

extern "C" void kernel_launch(void* const* d_in, const int* in_sizes, int n_in,
                              void* d_out, int out_size, void* d_ws, size_t ws_size,
                              hipStream_t stream) {
    const float* x        = (const float*)d_in[0];
    const float* hist_in  = (const float*)d_in[1];
    const float* logp_ref = (const float*)d_in[2];
    float* out = (float*)d_out;

    const int C = in_sizes[1] / BINS;            // 5
    const i64 total = (i64)in_sizes[0];
    const i64 nper = total / C;                  // B*L = 8388608

    // ---- workspace layout: [zeroed control/hist region][fixed-slot candidate buffer] ----
    char* w = (char*)d_ws;
    size_t off = 0;
    float* mv   = (float*)(w + off); off += 4 * ((C + 7) & ~7);
    u32* histA  = (u32*)(w + off); off += 4 * 1024 * C;
    u32* h256   = (u32*)(w + off); off += 4 * BINS * C;
    u32* oflow  = (u32*)(w + off); off += 4 * C;
    u32* flag   = (u32*)(w + off); off += 4 * C;
    u32* csel1  = (u32*)(w + off); off += 4 * 4 * C;
    u32* csel2  = (u32*)(w + off); off += 4 * 4 * C;
    u32* ch1024 = (u32*)(w + off); off += 4 * 1024 * C;
    u32* h2a    = (u32*)(w + off); off += 4 * 2048 * C;
    u32* h2b    = (u32*)(w + off); off += 4 * 2048 * C;
    u32* h3a    = (u32*)(w + off); off += 4 * 1024 * C;
    u32* h3b    = (u32*)(w + off); off += 4 * 1024 * C;
    u32* sel1   = (u32*)(w + off); off += 4 * 4 * C;
    u32* sel2   = (u32*)(w + off); off += 4 * 4 * C;
    u32* hB0    = (u32*)(w + off); off += 4 * 2048 * C;
    u32* hB1    = (u32*)(w + off); off += 4 * 2048 * C;
    u32* hC0    = (u32*)(w + off); off += 4 * 1024 * C;
    u32* hC1    = (u32*)(w + off); off += 4 * 1024 * C;
    const size_t zbytes = off;
    off = (off + 255) & ~(size_t)255;
    u32* cand = (u32*)(w + off);
    const i64 ntot = (i64)NBLK * SLOT;                       // padded entries per channel
    const size_t cand_bytes = (size_t)4 * (size_t)C * (size_t)ntot;   // ~21 MB
    const int do_cand = (ws_size >= off + cand_bytes) ? 1 : 0;

    hipMemsetAsync(d_ws, 0, zbytes, stream);

    const double virt = 0.99 * (double)(nper - 1);
    const i64 k0 = (i64)floor(virt);
    const double gamma = virt - (double)k0;
    const u32 needed = (u32)(nper - k0);         // top-count that must be candidates
    const u32 T0 = (u32)(ntot - (i64)needed);    // constant rank in padded multiset

    dim3 blk(256);
    dim3 grd(NBLK, (unsigned)C);
    dim3 grd16(16, (unsigned)C);
    dim3 grd128(128, (unsigned)C);

    k_pass1<<<grd, blk, 0, stream>>>(x, histA, cand, oflow, nper, do_cand);
    if (do_cand) {
        k_csel_hist1<<<grd16, blk, 0, stream>>>(cand, ch1024, ntot);
        k_csel_pick1<<<(unsigned)C, blk, 0, stream>>>(ch1024, oflow, flag, csel1, T0);
        k_csel_hist2<<<grd16, blk, 0, stream>>>(cand, flag, csel1, h2a, h2b, ntot);
        k_csel_pick2<<<(unsigned)C, blk, 0, stream>>>(h2a, h2b, flag, csel1, csel2);
        k_csel_hist3<<<grd16, blk, 0, stream>>>(cand, flag, csel2, h3a, h3b, ntot);
        k_csel_pick3<<<(unsigned)C, blk, 0, stream>>>(h3a, h3b, flag, csel2, mv, gamma);
    } else {
        k_flag_force<<<1, 64, 0, stream>>>(flag, C);
    }
    // fallback chain (flag-gated; early-exits when candidate path succeeded)
    k_scan_l1<<<(unsigned)C, blk, 0, stream>>>(histA, flag, sel1, (u32)k0);
    k_hist_l2<<<grd128, blk, 0, stream>>>(x, flag, sel1, hB0, hB1, nper);
    k_scan_l2<<<(unsigned)C, blk, 0, stream>>>(hB0, hB1, flag, sel1, sel2);
    k_hist_l3<<<grd128, blk, 0, stream>>>(x, flag, sel2, hC0, hC1, nper);
    k_finalize<<<(unsigned)C, blk, 0, stream>>>(hC0, hC1, flag, sel2, mv, gamma);
    // main path continues
    k_hist_idx<<<grd, blk, 0, stream>>>(x, mv, h256, nper);
    k_output<<<grd, blk, 0, stream>>>(x, mv, hist_in, logp_ref, h256, out, nper);
}

// Round 6
// 207.738 us; speedup vs baseline: 1.6927x; 1.6927x over previous
//
#include <hip/hip_runtime.h>
#include <math.h>

typedef unsigned int u32;
typedef unsigned long long u64;
typedef long long i64;

#define BINS 256
#define TBITS 0x40000000u    /* bit pattern of 2.0f : compaction threshold          */
#define OOBBITS 0x42000000u  /* bit pattern of 32.0f : cselA bin range end          */
#define A_BASE 131072u       /* TBITS >> 13                                         */
#define A_BINS 4096          /* covers |x| in [2, 32)                               */
#define B_BINS 8192          /* low 13 bits                                         */
#define SLOT 2048            /* per-block candidate slot (mean ~745, +48 sigma)     */
#define NBLK 512             /* blocks per channel for full passes                  */

// ---------------- helpers ----------------

// Bit-exact replica of the float32 numpy pipeline:
//   idx = trunc(min(|x|/mv, 1.0f) * 255.0f)   (*8 and /8 are exact pow2 ops)
__device__ __forceinline__ int bin_index_f32(float xv, float mv) {
    float r = __fdiv_rn(fabsf(xv), mv);
    r = fminf(r, 1.0f);
    return (int)__fmul_rn(r, 255.0f);
}

// Parallel rank-select over h[0..256*PER) for `target`; one thread writes
// res[0]=bucket, res[1]=target-cum_excl(bucket). Caller zeroes res, syncs after.
template<int PER>
__device__ void block_select(const u32* __restrict__ h, u32 target,
                             u32* ssum, u32* res) {
    const int t = threadIdx.x;
    u32 loc[PER];
    u32 s = 0;
    const int base = t * PER;
#pragma unroll
    for (int j = 0; j < PER; ++j) { loc[j] = h[base + j]; s += loc[j]; }
    ssum[t] = s;
    __syncthreads();
    for (int off = 1; off < 256; off <<= 1) {
        u32 add = (t >= off) ? ssum[t - off] : 0;
        __syncthreads();
        ssum[t] += add;
        __syncthreads();
    }
    u32 cum = ssum[t] - s;
#pragma unroll
    for (int j = 0; j < PER; ++j) {
        u32 cnt = loc[j];
        if (target >= cum && target < cum + cnt) { res[0] = (u32)(base + j); res[1] = target - cum; }
        cum += cnt;
    }
    __syncthreads();
}

// numpy float32 _lerp between exact order stats v0bits <= v1bits
__device__ __forceinline__ float np_lerp_f32(u32 v0bits, u32 v1bits, double gamma) {
    float v0 = __uint_as_float(v0bits);
    float v1 = __uint_as_float(v1bits);
    float dba = __fsub_rn(v1, v0);
    float q;
    if (gamma >= 0.5) q = __fsub_rn(v1, __fmul_rn(dba, (float)(1.0 - gamma)));
    else              q = __fadd_rn(v0, __fmul_rn(dba, (float)gamma));
    return fmaxf(q, 1e-8f);
}

// ---------------- pass 1: pure streaming threshold-compaction (no histogram) ----------------

__global__ __launch_bounds__(256) void k_pass1(const float* __restrict__ x, u32* __restrict__ cand,
                                               u32* __restrict__ oflow, i64 nper, int do_cand) {
    __shared__ u32 lbuf[SLOT];
    __shared__ u32 lcnt;
    const int c = blockIdx.y;
    if (threadIdx.x == 0) lcnt = 0;
    __syncthreads();
    const float* xc = x + (i64)c * nper;
    const i64 nv = nper >> 2;
    const float4* xv = (const float4*)xc;
    for (i64 i = (i64)blockIdx.x * 256 + threadIdx.x; i < nv; i += (i64)gridDim.x * 256) {
        float4 v = xv[i];
        u32 b;
        b = __float_as_uint(fabsf(v.x));
        if (b >= TBITS) { u32 p = atomicAdd(&lcnt, 1u); if (p < SLOT) lbuf[p] = b; }
        b = __float_as_uint(fabsf(v.y));
        if (b >= TBITS) { u32 p = atomicAdd(&lcnt, 1u); if (p < SLOT) lbuf[p] = b; }
        b = __float_as_uint(fabsf(v.z));
        if (b >= TBITS) { u32 p = atomicAdd(&lcnt, 1u); if (p < SLOT) lbuf[p] = b; }
        b = __float_as_uint(fabsf(v.w));
        if (b >= TBITS) { u32 p = atomicAdd(&lcnt, 1u); if (p < SLOT) lbuf[p] = b; }
    }
    if (blockIdx.x == 0 && threadIdx.x < (int)(nper & 3)) {
        u32 b = __float_as_uint(fabsf(xc[nv * 4 + threadIdx.x]));
        if (b >= TBITS) { u32 p = atomicAdd(&lcnt, 1u); if (p < SLOT) lbuf[p] = b; }
    }
    __syncthreads();
    if (threadIdx.x == 0 && lcnt > SLOT) {
        atomicExch(&oflow[c], 1u);   // idempotent: deterministic regardless of order
        lcnt = SLOT;
    }
    __syncthreads();
    if (do_cand) {
        const u32 cnt = lcnt;
        u32* slot = cand + ((i64)c * gridDim.x + blockIdx.x) * SLOT;
        for (u32 j = threadIdx.x; j < SLOT; j += 256)
            slot[j] = (j < cnt) ? lbuf[j] : 0u;   // pad = 0, below every candidate
    }
}

// ---------------- candidate select stage A (bits 31..13 -> 4096 offset bins) ----------------

__global__ __launch_bounds__(256) void k_cselA_hist(const u32* __restrict__ cand,
                                                    u32* __restrict__ gha, u32* __restrict__ goob, i64 ntot) {
    __shared__ u32 ha[A_BINS];
    __shared__ u32 loob;
    const int c = blockIdx.y;
    for (int i = threadIdx.x; i < A_BINS; i += 256) ha[i] = 0;
    if (threadIdx.x == 0) loob = 0;
    __syncthreads();
    const uint4* cd = (const uint4*)(cand + (i64)c * ntot);
    const i64 nv4 = ntot >> 2;
    for (i64 i = (i64)blockIdx.x * 256 + threadIdx.x; i < nv4; i += (i64)gridDim.x * 256) {
        uint4 v = cd[i];
        u32 b;
        b = v.x; if (b >= TBITS) { u32 bin = (b >> 13) - A_BASE; if (bin >= A_BINS) { atomicAdd(&loob, 1u); bin = A_BINS - 1; } atomicAdd(&ha[bin], 1u); }
        b = v.y; if (b >= TBITS) { u32 bin = (b >> 13) - A_BASE; if (bin >= A_BINS) { atomicAdd(&loob, 1u); bin = A_BINS - 1; } atomicAdd(&ha[bin], 1u); }
        b = v.z; if (b >= TBITS) { u32 bin = (b >> 13) - A_BASE; if (bin >= A_BINS) { atomicAdd(&loob, 1u); bin = A_BINS - 1; } atomicAdd(&ha[bin], 1u); }
        b = v.w; if (b >= TBITS) { u32 bin = (b >> 13) - A_BASE; if (bin >= A_BINS) { atomicAdd(&loob, 1u); bin = A_BINS - 1; } atomicAdd(&ha[bin], 1u); }
    }
    __syncthreads();
    for (int i = threadIdx.x; i < A_BINS; i += 256)
        if (ha[i]) atomicAdd(&gha[c * A_BINS + i], ha[i]);
    if (threadIdx.x == 0 && loob) atomicExch(&goob[c], 1u);
}

__global__ __launch_bounds__(256) void k_cselA_pick(const u32* __restrict__ gha,
                                                    const u32* __restrict__ oflow, const u32* __restrict__ goob,
                                                    u32* __restrict__ flag, u32* __restrict__ cselA, u32 needed) {
    __shared__ u32 ssum[256];
    __shared__ u32 pr[4];
    __shared__ u32 s_total;
    const int c = blockIdx.x;
    const int t = threadIdx.x;
    if (t < 4) pr[t] = 0;
    const u32* h = gha + c * A_BINS;
    u32 loc[16];
    u32 s = 0;
    const int base = t * 16;
#pragma unroll
    for (int j = 0; j < 16; ++j) { loc[j] = h[base + j]; s += loc[j]; }
    ssum[t] = s;
    __syncthreads();
    for (int off = 1; off < 256; off <<= 1) {
        u32 add = (t >= off) ? ssum[t - off] : 0;
        __syncthreads();
        ssum[t] += add;
        __syncthreads();
    }
    if (t == 255) s_total = ssum[255];
    __syncthreads();
    const u32 total = s_total;
    const u32 bad = (oflow[c] != 0) || (goob[c] != 0) || (total < needed) || (needed < 2);
    if (t == 0) flag[c] = bad;
    if (bad) return;
    const u32 t0 = total - needed;
    const u32 t1 = t0 + 1;
    u32 cum = ssum[t] - s;
#pragma unroll
    for (int j = 0; j < 16; ++j) {
        u32 cnt = loc[j];
        if (t0 >= cum && t0 < cum + cnt) { pr[0] = (u32)(base + j); pr[1] = t0 - cum; }
        if (t1 >= cum && t1 < cum + cnt) { pr[2] = (u32)(base + j); pr[3] = t1 - cum; }
        cum += cnt;
    }
    __syncthreads();
    if (t == 0) {
        cselA[c * 4 + 0] = pr[0]; cselA[c * 4 + 1] = pr[1];
        cselA[c * 4 + 2] = pr[2]; cselA[c * 4 + 3] = pr[3];
    }
}

// ---------------- candidate select stage B (bits 12..0 -> 8192 bins, two chains) ----------------

__global__ __launch_bounds__(256) void k_cselB_hist(const u32* __restrict__ cand, const u32* __restrict__ flag,
                                                    const u32* __restrict__ cselA,
                                                    u32* __restrict__ g3a, u32* __restrict__ g3b, i64 ntot) {
    const int c = blockIdx.y;
    if (flag[c]) return;
    __shared__ u32 la[B_BINS], lb[B_BINS];
    for (int i = threadIdx.x; i < B_BINS; i += 256) { la[i] = 0; lb[i] = 0; }
    __syncthreads();
    const u32 topA0 = A_BASE + cselA[c * 4 + 0];
    const u32 topA1 = A_BASE + cselA[c * 4 + 2];
    const u32* cd = cand + (i64)c * ntot;
    for (i64 i = (i64)blockIdx.x * 256 + threadIdx.x; i < ntot; i += (i64)gridDim.x * 256) {
        u32 v = cd[i];
        if (v >= TBITS) {
            u32 tbin = v >> 13;
            if (tbin == topA0) atomicAdd(&la[v & (B_BINS - 1)], 1u);
            if (tbin == topA1) atomicAdd(&lb[v & (B_BINS - 1)], 1u);
        }
    }
    __syncthreads();
    for (int i = threadIdx.x; i < B_BINS; i += 256) {
        if (la[i]) atomicAdd(&g3a[c * B_BINS + i], la[i]);
        if (lb[i]) atomicAdd(&g3b[c * B_BINS + i], lb[i]);
    }
}

__global__ __launch_bounds__(256) void k_cselB_pick(const u32* __restrict__ g3a, const u32* __restrict__ g3b,
                                                    const u32* __restrict__ flag, const u32* __restrict__ cselA,
                                                    float* __restrict__ mv, double gamma) {
    __shared__ u32 ssum[256];
    __shared__ u32 pr[4];
    const int c = blockIdx.x;
    if (flag[c]) return;
    if (threadIdx.x < 4) pr[threadIdx.x] = 0;
    __syncthreads();
    block_select<32>(g3a + c * B_BINS, cselA[c * 4 + 1], ssum, &pr[0]);
    block_select<32>(g3b + c * B_BINS, cselA[c * 4 + 3], ssum, &pr[2]);
    if (threadIdx.x == 0) {
        u32 v0bits = ((A_BASE + cselA[c * 4 + 0]) << 13) | pr[0];
        u32 v1bits = ((A_BASE + cselA[c * 4 + 2]) << 13) | pr[2];
        mv[c] = np_lerp_f32(v0bits, v1bits, gamma);
    }
}

__global__ void k_flag_force(u32* __restrict__ flag, int C) {
    if (threadIdx.x < C) flag[threadIdx.x] = 1u;
}

// ---------------- fallback: self-contained in-block 3-level exact select ----------------
// One block per flagged channel; early-exits otherwise. Never triggers for sane data.

__global__ __launch_bounds__(256) void k_fallback(const float* __restrict__ x, const u32* __restrict__ flag,
                                                  float* __restrict__ mv, i64 nper, u32 k0, double gamma) {
    const int c = blockIdx.x;
    if (!flag[c]) return;
    __shared__ u32 h0[2048], h1[2048];
    __shared__ u32 ssum[256];
    __shared__ u32 pr[4];
    __shared__ u32 st[4];
    const float* xc = x + (i64)c * nper;
    const i64 nv = nper >> 2;
    const int rem = (int)(nper & 3);
    const float4* xv = (const float4*)xc;
    const int t = threadIdx.x;

    // level 1: bits 31..21 (1024 bins)
    for (int i = t; i < 1024; i += 256) h0[i] = 0;
    __syncthreads();
    for (i64 i = t; i < nv; i += 256) {
        float4 v = xv[i];
        atomicAdd(&h0[__float_as_uint(fabsf(v.x)) >> 21], 1u);
        atomicAdd(&h0[__float_as_uint(fabsf(v.y)) >> 21], 1u);
        atomicAdd(&h0[__float_as_uint(fabsf(v.z)) >> 21], 1u);
        atomicAdd(&h0[__float_as_uint(fabsf(v.w)) >> 21], 1u);
    }
    if (t < rem) atomicAdd(&h0[__float_as_uint(fabsf(xc[nv * 4 + t])) >> 21], 1u);
    __syncthreads();
    if (t < 4) pr[t] = 0;
    __syncthreads();
    block_select<4>(h0, k0, ssum, &pr[0]);
    block_select<4>(h0, k0 + 1, ssum, &pr[2]);
    if (t < 4) st[t] = pr[t];
    __syncthreads();

    // level 2: bits 20..10 (2048 bins, two chains)
    const u32 p0 = st[0], p1 = st[2];
    for (int i = t; i < 2048; i += 256) { h0[i] = 0; h1[i] = 0; }
    __syncthreads();
    for (i64 i = t; i < nv; i += 256) {
        float4 v = xv[i];
        u32 b;
        b = __float_as_uint(fabsf(v.x));
        if ((b >> 21) == p0) atomicAdd(&h0[(b >> 10) & 2047], 1u);
        if ((b >> 21) == p1) atomicAdd(&h1[(b >> 10) & 2047], 1u);
        b = __float_as_uint(fabsf(v.y));
        if ((b >> 21) == p0) atomicAdd(&h0[(b >> 10) & 2047], 1u);
        if ((b >> 21) == p1) atomicAdd(&h1[(b >> 10) & 2047], 1u);
        b = __float_as_uint(fabsf(v.z));
        if ((b >> 21) == p0) atomicAdd(&h0[(b >> 10) & 2047], 1u);
        if ((b >> 21) == p1) atomicAdd(&h1[(b >> 10) & 2047], 1u);
        b = __float_as_uint(fabsf(v.w));
        if ((b >> 21) == p0) atomicAdd(&h0[(b >> 10) & 2047], 1u);
        if ((b >> 21) == p1) atomicAdd(&h1[(b >> 10) & 2047], 1u);
    }
    if (t < rem) {
        u32 b = __float_as_uint(fabsf(xc[nv * 4 + t]));
        if ((b >> 21) == p0) atomicAdd(&h0[(b >> 10) & 2047], 1u);
        if ((b >> 21) == p1) atomicAdd(&h1[(b >> 10) & 2047], 1u);
    }
    __syncthreads();
    if (t < 4) pr[t] = 0;
    __syncthreads();
    block_select<8>(h0, st[1], ssum, &pr[0]);
    block_select<8>(h1, st[3], ssum, &pr[2]);
    if (t == 0) { st[0] = (p0 << 11) | pr[0]; st[1] = pr[1]; st[2] = (p1 << 11) | pr[2]; st[3] = pr[3]; }
    __syncthreads();

    // level 3: bits 9..0 (1024 bins, two chains)
    const u32 q0 = st[0], q1 = st[2];
    for (int i = t; i < 1024; i += 256) { h0[i] = 0; h1[i] = 0; }
    __syncthreads();
    for (i64 i = t; i < nv; i += 256) {
        float4 v = xv[i];
        u32 b;
        b = __float_as_uint(fabsf(v.x));
        if ((b >> 10) == q0) atomicAdd(&h0[b & 1023], 1u);
        if ((b >> 10) == q1) atomicAdd(&h1[b & 1023], 1u);
        b = __float_as_uint(fabsf(v.y));
        if ((b >> 10) == q0) atomicAdd(&h0[b & 1023], 1u);
        if ((b >> 10) == q1) atomicAdd(&h1[b & 1023], 1u);
        b = __float_as_uint(fabsf(v.z));
        if ((b >> 10) == q0) atomicAdd(&h0[b & 1023], 1u);
        if ((b >> 10) == q1) atomicAdd(&h1[b & 1023], 1u);
        b = __float_as_uint(fabsf(v.w));
        if ((b >> 10) == q0) atomicAdd(&h0[b & 1023], 1u);
        if ((b >> 10) == q1) atomicAdd(&h1[b & 1023], 1u);
    }
    if (t < rem) {
        u32 b = __float_as_uint(fabsf(xc[nv * 4 + t]));
        if ((b >> 10) == q0) atomicAdd(&h0[b & 1023], 1u);
        if ((b >> 10) == q1) atomicAdd(&h1[b & 1023], 1u);
    }
    __syncthreads();
    if (t < 4) pr[t] = 0;
    __syncthreads();
    block_select<4>(h0, st[1], ssum, &pr[0]);
    block_select<4>(h1, st[3], ssum, &pr[2]);
    if (t == 0) {
        u32 v0bits = (q0 << 10) | pr[0];
        u32 v1bits = (q1 << 10) | pr[2];
        mv[c] = np_lerp_f32(v0bits, v1bits, gamma);
    }
}

// ---------------- 256-bin index histogram (round-3 verbatim) ----------------

__global__ __launch_bounds__(256) void k_hist_idx(const float* __restrict__ x, const float* __restrict__ mv,
                                                  u32* __restrict__ h256, i64 nper) {
    __shared__ u32 lh[8][257];
    const int c = blockIdx.y;
    const float m = mv[c];
    for (int i = threadIdx.x; i < 8 * 257; i += 256) (&lh[0][0])[i] = 0;
    __syncthreads();
    const float* xc = x + (i64)c * nper;
    const i64 nv = nper >> 2;
    const int copy = threadIdx.x & 7;
    const float4* xv = (const float4*)xc;
    for (i64 i = (i64)blockIdx.x * 256 + threadIdx.x; i < nv; i += (i64)gridDim.x * 256) {
        float4 v = xv[i];
        atomicAdd(&lh[copy][bin_index_f32(v.x, m)], 1u);
        atomicAdd(&lh[copy][bin_index_f32(v.y, m)], 1u);
        atomicAdd(&lh[copy][bin_index_f32(v.z, m)], 1u);
        atomicAdd(&lh[copy][bin_index_f32(v.w, m)], 1u);
    }
    if (blockIdx.x == 0 && threadIdx.x < (int)(nper & 3)) {
        atomicAdd(&lh[copy][bin_index_f32(xc[nv * 4 + threadIdx.x], m)], 1u);
    }
    __syncthreads();
    for (int i = threadIdx.x; i < BINS; i += 256) {
        u32 s = 0;
#pragma unroll
        for (int k = 0; k < 8; ++k) s += lh[k][i];
        if (s) atomicAdd(&h256[c * BINS + i], s);
    }
}

// ---------------- mask table (round-3 verbatim) ----------------

__global__ void k_mask_table(const float* __restrict__ hist_in, const float* __restrict__ logp_ref,
                             const u32* __restrict__ h256, double* __restrict__ mask) {
    __shared__ double sm[BINS];
    __shared__ double ssum;
    const int c = blockIdx.x;
    const int b = threadIdx.x;  // 256 threads
    float h = hist_in[c * BINS + b];
    float n = (float)h256[c * BINS + b];
    float t = __fadd_rn(__fmul_rn(0.98f, h), __fmul_rn(0.02f, n));
    float smf = __fadd_rn(t, 1e-8f);
    double smoothed = (double)smf;
    sm[b] = smoothed;
    __syncthreads();
    if (b == 0) { double s = 0.0; for (int i = 0; i < BINS; ++i) s += sm[i]; ssum = s; }
    __syncthreads();
    double logp_obs = log(smoothed / ssum);
    double Lam = (double)logp_ref[c * BINS + b] - logp_obs;
    mask[c * BINS + b] = 1.0 / (1.0 + exp(Lam + 2.0));   // THRESH = -2
}

// ---------------- output (round-3 verbatim) ----------------

__global__ __launch_bounds__(256) void k_output(const float* __restrict__ x, const float* __restrict__ mv,
                                                const double* __restrict__ mask, float* __restrict__ out, i64 nper) {
    const int c = blockIdx.y;
    const float m = mv[c];
    const double* mt = mask + c * BINS;
    const float* xc = x + (i64)c * nper;
    float* oc = out + (i64)c * nper;
    const i64 nv = nper >> 2;
    const float4* xv = (const float4*)xc;
    float4* ov = (float4*)oc;
    for (i64 i = (i64)blockIdx.x * 256 + threadIdx.x; i < nv; i += (i64)gridDim.x * 256) {
        float4 v = xv[i];
        float4 o;
        o.x = (float)((double)v.x * mt[bin_index_f32(v.x, m)]);
        o.y = (float)((double)v.y * mt[bin_index_f32(v.y, m)]);
        o.z = (float)((double)v.z * mt[bin_index_f32(v.z, m)]);
        o.w = (float)((double)v.w * mt[bin_index_f32(v.w, m)]);
        ov[i] = o;
    }
    if (blockIdx.x == 0 && threadIdx.x < (int)(nper & 3)) {
        i64 i = nv * 4 + threadIdx.x;
        float v = xc[i];
        oc[i] = (float)((double)v * mt[bin_index_f32(v, m)]);
    }
}

// ---------------- launch ----------------

extern "C" void kernel_launch(void* const* d_in, const int* in_sizes, int n_in,
                              void* d_out, int out_size, void* d_ws, size_t ws_size,
                              hipStream_t stream) {
    const float* x        = (const float*)d_in[0];
    const float* hist_in  = (const float*)d_in[1];
    const float* logp_ref = (const float*)d_in[2];
    float* out = (float*)d_out;

    const int C = in_sizes[1] / BINS;            // 5
    const i64 total = (i64)in_sizes[0];
    const i64 nper = total / C;                  // B*L = 8388608

    // ---- workspace: [zeroed control/hist region][fixed-slot candidate buffer] ----
    char* w = (char*)d_ws;
    size_t off = 0;
    float*  mv   = (float*)(w + off);  off += 4 * ((C + 7) & ~7);
    double* mask = (double*)(w + off); off += 8 * BINS * C;
    u32* h256   = (u32*)(w + off); off += 4 * BINS * C;
    u32* oflow  = (u32*)(w + off); off += 4 * C;
    u32* goob   = (u32*)(w + off); off += 4 * C;
    u32* flag   = (u32*)(w + off); off += 4 * C;
    u32* cselA  = (u32*)(w + off); off += 4 * 4 * C;
    u32* gha    = (u32*)(w + off); off += 4 * A_BINS * C;
    u32* g3a    = (u32*)(w + off); off += 4 * B_BINS * C;
    u32* g3b    = (u32*)(w + off); off += 4 * B_BINS * C;
    const size_t zbytes = off;
    off = (off + 255) & ~(size_t)255;
    u32* cand = (u32*)(w + off);
    const i64 ntot = (i64)NBLK * SLOT;                                // entries per channel
    const size_t cand_bytes = (size_t)4 * (size_t)C * (size_t)ntot;   // ~21 MB
    const int do_cand = (ws_size >= off + cand_bytes) ? 1 : 0;

    hipMemsetAsync(d_ws, 0, zbytes, stream);

    const double virt = 0.99 * (double)(nper - 1);
    const i64 k0 = (i64)floor(virt);
    const double gamma = virt - (double)k0;
    const u32 needed = (u32)(nper - k0);   // top-count that must be in candidates

    dim3 blk(256);
    dim3 grd(NBLK, (unsigned)C);
    dim3 grd64(64, (unsigned)C);

    k_pass1<<<grd, blk, 0, stream>>>(x, cand, oflow, nper, do_cand);
    if (do_cand) {
        k_cselA_hist<<<grd64, blk, 0, stream>>>(cand, gha, goob, ntot);
        k_cselA_pick<<<(unsigned)C, blk, 0, stream>>>(gha, oflow, goob, flag, cselA, needed);
        k_cselB_hist<<<grd64, blk, 0, stream>>>(cand, flag, cselA, g3a, g3b, ntot);
        k_cselB_pick<<<(unsigned)C, blk, 0, stream>>>(g3a, g3b, flag, cselA, mv, gamma);
    } else {
        k_flag_force<<<1, 64, 0, stream>>>(flag, C);
    }
    // self-contained fallback (1 block per flagged channel; early-exits otherwise)
    k_fallback<<<(unsigned)C, blk, 0, stream>>>(x, flag, mv, nper, (u32)k0, gamma);
    // main path
    k_hist_idx<<<grd, blk, 0, stream>>>(x, mv, h256, nper);
    k_mask_table<<<(unsigned)C, BINS, 0, stream>>>(hist_in, logp_ref, h256, mask);
    k_output<<<grd, blk, 0, stream>>>(x, mv, mask, out, nper);
}

// Round 7
// 194.862 us; speedup vs baseline: 1.8046x; 1.0661x over previous
//
#include <hip/hip_runtime.h>
#include <math.h>

typedef unsigned int u32;
typedef unsigned long long u64;
typedef long long i64;

#define BINS 256
#define TBITS 0x40000000u    /* bit pattern of 2.0f : compaction threshold          */
#define A_BASE 131072u       /* TBITS >> 13                                         */
#define A_BINS 4096          /* covers |x| in [2, 32)                               */
#define B_BINS 8192          /* low 13 bits                                         */
#define SLOT 1536            /* per-block candidate slot (mean ~754, +29 sigma)     */
#define NBLK 512             /* blocks per channel for full passes                  */

// ---------------- helpers ----------------

// Bit-exact replica of the float32 numpy pipeline:
//   idx = trunc(min(|x|/mv, 1.0f) * 255.0f)   (*8 and /8 are exact pow2 ops)
__device__ __forceinline__ int bin_index_f32(float xv, float mv) {
    float r = __fdiv_rn(fabsf(xv), mv);
    r = fminf(r, 1.0f);
    return (int)__fmul_rn(r, 255.0f);
}

// Parallel rank-select over h[0..256*PER) for `target`; one thread writes
// res[0]=bucket, res[1]=target-cum_excl(bucket). Caller zeroes res, syncs after.
template<int PER>
__device__ void block_select(const u32* __restrict__ h, u32 target,
                             u32* ssum, u32* res) {
    const int t = threadIdx.x;
    u32 loc[PER];
    u32 s = 0;
    const int base = t * PER;
#pragma unroll
    for (int j = 0; j < PER; ++j) { loc[j] = h[base + j]; s += loc[j]; }
    ssum[t] = s;
    __syncthreads();
    for (int off = 1; off < 256; off <<= 1) {
        u32 add = (t >= off) ? ssum[t - off] : 0;
        __syncthreads();
        ssum[t] += add;
        __syncthreads();
    }
    u32 cum = ssum[t] - s;
#pragma unroll
    for (int j = 0; j < PER; ++j) {
        u32 cnt = loc[j];
        if (target >= cum && target < cum + cnt) { res[0] = (u32)(base + j); res[1] = target - cum; }
        cum += cnt;
    }
    __syncthreads();
}

// numpy float32 _lerp between exact order stats v0bits <= v1bits
__device__ __forceinline__ float np_lerp_f32(u32 v0bits, u32 v1bits, double gamma) {
    float v0 = __uint_as_float(v0bits);
    float v1 = __uint_as_float(v1bits);
    float dba = __fsub_rn(v1, v0);
    float q;
    if (gamma >= 0.5) q = __fsub_rn(v1, __fmul_rn(dba, (float)(1.0 - gamma)));
    else              q = __fadd_rn(v0, __fmul_rn(dba, (float)gamma));
    return fmaxf(q, 1e-8f);
}

// ---------------- pass 1: streaming threshold-compaction + fused 4096-bin candidate hist ----------------

__global__ __launch_bounds__(256) void k_pass1(const float* __restrict__ x, u32* __restrict__ cand,
                                               u32* __restrict__ gha, u32* __restrict__ oflow,
                                               u32* __restrict__ goob, i64 nper, int do_cand) {
    __shared__ u32 lbuf[SLOT];
    __shared__ u32 lha[A_BINS];
    __shared__ u32 lcnt, loob;
    const int c = blockIdx.y;
    for (int i = threadIdx.x; i < A_BINS; i += 256) lha[i] = 0;
    if (threadIdx.x == 0) { lcnt = 0; loob = 0; }
    __syncthreads();
    const float* xc = x + (i64)c * nper;
    const i64 nv2 = nper >> 3;
    const float4* xv = (const float4*)xc;
    for (i64 i = (i64)blockIdx.x * 256 + threadIdx.x; i < nv2; i += (i64)gridDim.x * 256) {
        float4 a = xv[2 * i], b = xv[2 * i + 1];
        u32 bb[8];
        bb[0] = __float_as_uint(fabsf(a.x)); bb[1] = __float_as_uint(fabsf(a.y));
        bb[2] = __float_as_uint(fabsf(a.z)); bb[3] = __float_as_uint(fabsf(a.w));
        bb[4] = __float_as_uint(fabsf(b.x)); bb[5] = __float_as_uint(fabsf(b.y));
        bb[6] = __float_as_uint(fabsf(b.z)); bb[7] = __float_as_uint(fabsf(b.w));
#pragma unroll
        for (int k = 0; k < 8; ++k) {
            if (bb[k] >= TBITS) {
                u32 p = atomicAdd(&lcnt, 1u);
                if (p < SLOT) lbuf[p] = bb[k];
                u32 bin = (bb[k] >> 13) - A_BASE;
                if (bin >= A_BINS) { atomicAdd(&loob, 1u); bin = A_BINS - 1; }
                atomicAdd(&lha[bin], 1u);
            }
        }
    }
    if (blockIdx.x == 0 && threadIdx.x < (int)(nper & 7)) {
        u32 b = __float_as_uint(fabsf(xc[nv2 * 8 + threadIdx.x]));
        if (b >= TBITS) {
            u32 p = atomicAdd(&lcnt, 1u);
            if (p < SLOT) lbuf[p] = b;
            u32 bin = (b >> 13) - A_BASE;
            if (bin >= A_BINS) { atomicAdd(&loob, 1u); bin = A_BINS - 1; }
            atomicAdd(&lha[bin], 1u);
        }
    }
    __syncthreads();
    for (int i = threadIdx.x; i < A_BINS; i += 256)
        if (lha[i]) atomicAdd(&gha[c * A_BINS + i], lha[i]);
    if (threadIdx.x == 0) {
        if (loob) atomicExch(&goob[c], 1u);
        if (lcnt > SLOT) { atomicExch(&oflow[c], 1u); lcnt = SLOT; }
    }
    __syncthreads();
    if (do_cand) {
        const u32 cnt = lcnt;
        u32* slot = cand + ((i64)c * gridDim.x + blockIdx.x) * SLOT;
        for (u32 j = threadIdx.x; j < SLOT; j += 256)
            slot[j] = (j < cnt) ? lbuf[j] : 0u;   // pad = 0, below every candidate
    }
}

// ---------------- candidate select stage A pick (4096 offset bins) ----------------

__global__ __launch_bounds__(256) void k_cselA_pick(const u32* __restrict__ gha,
                                                    const u32* __restrict__ oflow, const u32* __restrict__ goob,
                                                    u32* __restrict__ flag, u32* __restrict__ cselA, u32 needed) {
    __shared__ u32 ssum[256];
    __shared__ u32 pr[4];
    __shared__ u32 s_total;
    const int c = blockIdx.x;
    const int t = threadIdx.x;
    if (t < 4) pr[t] = 0;
    const u32* h = gha + c * A_BINS;
    u32 loc[16];
    u32 s = 0;
    const int base = t * 16;
#pragma unroll
    for (int j = 0; j < 16; ++j) { loc[j] = h[base + j]; s += loc[j]; }
    ssum[t] = s;
    __syncthreads();
    for (int off = 1; off < 256; off <<= 1) {
        u32 add = (t >= off) ? ssum[t - off] : 0;
        __syncthreads();
        ssum[t] += add;
        __syncthreads();
    }
    if (t == 255) s_total = ssum[255];
    __syncthreads();
    const u32 total = s_total;
    const u32 bad = (oflow[c] != 0) || (goob[c] != 0) || (total < needed) || (needed < 2);
    if (t == 0) flag[c] = bad;
    if (bad) return;
    const u32 t0 = total - needed;
    const u32 t1 = t0 + 1;
    u32 cum = ssum[t] - s;
#pragma unroll
    for (int j = 0; j < 16; ++j) {
        u32 cnt = loc[j];
        if (t0 >= cum && t0 < cum + cnt) { pr[0] = (u32)(base + j); pr[1] = t0 - cum; }
        if (t1 >= cum && t1 < cum + cnt) { pr[2] = (u32)(base + j); pr[3] = t1 - cum; }
        cum += cnt;
    }
    __syncthreads();
    if (t == 0) {
        cselA[c * 4 + 0] = pr[0]; cselA[c * 4 + 1] = pr[1];
        cselA[c * 4 + 2] = pr[2]; cselA[c * 4 + 3] = pr[3];
    }
}

// ---------------- candidate select stage B (bits 12..0 -> 8192 bins, two chains) ----------------

__global__ __launch_bounds__(256) void k_cselB_hist(const u32* __restrict__ cand, const u32* __restrict__ flag,
                                                    const u32* __restrict__ cselA,
                                                    u32* __restrict__ g3a, u32* __restrict__ g3b, i64 ntot) {
    const int c = blockIdx.y;
    if (flag[c]) return;
    __shared__ u32 la[B_BINS], lb[B_BINS];
    for (int i = threadIdx.x; i < B_BINS; i += 256) { la[i] = 0; lb[i] = 0; }
    __syncthreads();
    const u32 topA0 = A_BASE + cselA[c * 4 + 0];
    const u32 topA1 = A_BASE + cselA[c * 4 + 2];
    const uint4* cd = (const uint4*)(cand + (i64)c * ntot);
    const i64 nv4 = ntot >> 2;
    for (i64 i = (i64)blockIdx.x * 256 + threadIdx.x; i < nv4; i += (i64)gridDim.x * 256) {
        uint4 v = cd[i];
        u32 b;
        b = v.x;
        if (b >= TBITS) { u32 tb = b >> 13; if (tb == topA0) atomicAdd(&la[b & (B_BINS - 1)], 1u); if (tb == topA1) atomicAdd(&lb[b & (B_BINS - 1)], 1u); }
        b = v.y;
        if (b >= TBITS) { u32 tb = b >> 13; if (tb == topA0) atomicAdd(&la[b & (B_BINS - 1)], 1u); if (tb == topA1) atomicAdd(&lb[b & (B_BINS - 1)], 1u); }
        b = v.z;
        if (b >= TBITS) { u32 tb = b >> 13; if (tb == topA0) atomicAdd(&la[b & (B_BINS - 1)], 1u); if (tb == topA1) atomicAdd(&lb[b & (B_BINS - 1)], 1u); }
        b = v.w;
        if (b >= TBITS) { u32 tb = b >> 13; if (tb == topA0) atomicAdd(&la[b & (B_BINS - 1)], 1u); if (tb == topA1) atomicAdd(&lb[b & (B_BINS - 1)], 1u); }
    }
    __syncthreads();
    for (int i = threadIdx.x; i < B_BINS; i += 256) {
        if (la[i]) atomicAdd(&g3a[c * B_BINS + i], la[i]);
        if (lb[i]) atomicAdd(&g3b[c * B_BINS + i], lb[i]);
    }
}

__global__ __launch_bounds__(256) void k_cselB_pick(const u32* __restrict__ g3a, const u32* __restrict__ g3b,
                                                    const u32* __restrict__ flag, const u32* __restrict__ cselA,
                                                    float* __restrict__ mv, double gamma) {
    __shared__ u32 ssum[256];
    __shared__ u32 pr[4];
    const int c = blockIdx.x;
    if (flag[c]) return;
    if (threadIdx.x < 4) pr[threadIdx.x] = 0;
    __syncthreads();
    block_select<32>(g3a + c * B_BINS, cselA[c * 4 + 1], ssum, &pr[0]);
    block_select<32>(g3b + c * B_BINS, cselA[c * 4 + 3], ssum, &pr[2]);
    if (threadIdx.x == 0) {
        u32 v0bits = ((A_BASE + cselA[c * 4 + 0]) << 13) | pr[0];
        u32 v1bits = ((A_BASE + cselA[c * 4 + 2]) << 13) | pr[2];
        mv[c] = np_lerp_f32(v0bits, v1bits, gamma);
    }
}

__global__ void k_flag_force(u32* __restrict__ flag, int C) {
    if (threadIdx.x < C) flag[threadIdx.x] = 1u;
}

// ---------------- fallback: self-contained in-block 3-level exact select ----------------
// One block per flagged channel; early-exits otherwise. Never triggers for sane data.

__global__ __launch_bounds__(256) void k_fallback(const float* __restrict__ x, const u32* __restrict__ flag,
                                                  float* __restrict__ mv, i64 nper, u32 k0, double gamma) {
    const int c = blockIdx.x;
    if (!flag[c]) return;
    __shared__ u32 h0[2048], h1[2048];
    __shared__ u32 ssum[256];
    __shared__ u32 pr[4];
    __shared__ u32 st[4];
    const float* xc = x + (i64)c * nper;
    const i64 nv = nper >> 2;
    const int rem = (int)(nper & 3);
    const float4* xv = (const float4*)xc;
    const int t = threadIdx.x;

    // level 1: bits 31..21 (1024 bins)
    for (int i = t; i < 1024; i += 256) h0[i] = 0;
    __syncthreads();
    for (i64 i = t; i < nv; i += 256) {
        float4 v = xv[i];
        atomicAdd(&h0[__float_as_uint(fabsf(v.x)) >> 21], 1u);
        atomicAdd(&h0[__float_as_uint(fabsf(v.y)) >> 21], 1u);
        atomicAdd(&h0[__float_as_uint(fabsf(v.z)) >> 21], 1u);
        atomicAdd(&h0[__float_as_uint(fabsf(v.w)) >> 21], 1u);
    }
    if (t < rem) atomicAdd(&h0[__float_as_uint(fabsf(xc[nv * 4 + t])) >> 21], 1u);
    __syncthreads();
    if (t < 4) pr[t] = 0;
    __syncthreads();
    block_select<4>(h0, k0, ssum, &pr[0]);
    block_select<4>(h0, k0 + 1, ssum, &pr[2]);
    if (t < 4) st[t] = pr[t];
    __syncthreads();

    // level 2: bits 20..10 (2048 bins, two chains)
    const u32 p0 = st[0], p1 = st[2];
    for (int i = t; i < 2048; i += 256) { h0[i] = 0; h1[i] = 0; }
    __syncthreads();
    for (i64 i = t; i < nv; i += 256) {
        float4 v = xv[i];
        u32 b;
        b = __float_as_uint(fabsf(v.x));
        if ((b >> 21) == p0) atomicAdd(&h0[(b >> 10) & 2047], 1u);
        if ((b >> 21) == p1) atomicAdd(&h1[(b >> 10) & 2047], 1u);
        b = __float_as_uint(fabsf(v.y));
        if ((b >> 21) == p0) atomicAdd(&h0[(b >> 10) & 2047], 1u);
        if ((b >> 21) == p1) atomicAdd(&h1[(b >> 10) & 2047], 1u);
        b = __float_as_uint(fabsf(v.z));
        if ((b >> 21) == p0) atomicAdd(&h0[(b >> 10) & 2047], 1u);
        if ((b >> 21) == p1) atomicAdd(&h1[(b >> 10) & 2047], 1u);
        b = __float_as_uint(fabsf(v.w));
        if ((b >> 21) == p0) atomicAdd(&h0[(b >> 10) & 2047], 1u);
        if ((b >> 21) == p1) atomicAdd(&h1[(b >> 10) & 2047], 1u);
    }
    if (t < rem) {
        u32 b = __float_as_uint(fabsf(xc[nv * 4 + t]));
        if ((b >> 21) == p0) atomicAdd(&h0[(b >> 10) & 2047], 1u);
        if ((b >> 21) == p1) atomicAdd(&h1[(b >> 10) & 2047], 1u);
    }
    __syncthreads();
    if (t < 4) pr[t] = 0;
    __syncthreads();
    block_select<8>(h0, st[1], ssum, &pr[0]);
    block_select<8>(h1, st[3], ssum, &pr[2]);
    if (t == 0) { st[0] = (p0 << 11) | pr[0]; st[1] = pr[1]; st[2] = (p1 << 11) | pr[2]; st[3] = pr[3]; }
    __syncthreads();

    // level 3: bits 9..0 (1024 bins, two chains)
    const u32 q0 = st[0], q1 = st[2];
    for (int i = t; i < 1024; i += 256) { h0[i] = 0; h1[i] = 0; }
    __syncthreads();
    for (i64 i = t; i < nv; i += 256) {
        float4 v = xv[i];
        u32 b;
        b = __float_as_uint(fabsf(v.x));
        if ((b >> 10) == q0) atomicAdd(&h0[b & 1023], 1u);
        if ((b >> 10) == q1) atomicAdd(&h1[b & 1023], 1u);
        b = __float_as_uint(fabsf(v.y));
        if ((b >> 10) == q0) atomicAdd(&h0[b & 1023], 1u);
        if ((b >> 10) == q1) atomicAdd(&h1[b & 1023], 1u);
        b = __float_as_uint(fabsf(v.z));
        if ((b >> 10) == q0) atomicAdd(&h0[b & 1023], 1u);
        if ((b >> 10) == q1) atomicAdd(&h1[b & 1023], 1u);
        b = __float_as_uint(fabsf(v.w));
        if ((b >> 10) == q0) atomicAdd(&h0[b & 1023], 1u);
        if ((b >> 10) == q1) atomicAdd(&h1[b & 1023], 1u);
    }
    if (t < rem) {
        u32 b = __float_as_uint(fabsf(xc[nv * 4 + t]));
        if ((b >> 10) == q0) atomicAdd(&h0[b & 1023], 1u);
        if ((b >> 10) == q1) atomicAdd(&h1[b & 1023], 1u);
    }
    __syncthreads();
    if (t < 4) pr[t] = 0;
    __syncthreads();
    block_select<4>(h0, st[1], ssum, &pr[0]);
    block_select<4>(h1, st[3], ssum, &pr[2]);
    if (t == 0) {
        u32 v0bits = (q0 << 10) | pr[0];
        u32 v1bits = (q1 << 10) | pr[2];
        mv[c] = np_lerp_f32(v0bits, v1bits, gamma);
    }
}

// ---------------- 256-bin index histogram (x2 unroll) ----------------

__global__ __launch_bounds__(256) void k_hist_idx(const float* __restrict__ x, const float* __restrict__ mv,
                                                  u32* __restrict__ h256, i64 nper) {
    __shared__ u32 lh[8][257];
    const int c = blockIdx.y;
    const float m = mv[c];
    for (int i = threadIdx.x; i < 8 * 257; i += 256) (&lh[0][0])[i] = 0;
    __syncthreads();
    const float* xc = x + (i64)c * nper;
    const i64 nv2 = nper >> 3;
    const int copy = threadIdx.x & 7;
    const float4* xv = (const float4*)xc;
    for (i64 i = (i64)blockIdx.x * 256 + threadIdx.x; i < nv2; i += (i64)gridDim.x * 256) {
        float4 a = xv[2 * i], b = xv[2 * i + 1];
        atomicAdd(&lh[copy][bin_index_f32(a.x, m)], 1u);
        atomicAdd(&lh[copy][bin_index_f32(a.y, m)], 1u);
        atomicAdd(&lh[copy][bin_index_f32(a.z, m)], 1u);
        atomicAdd(&lh[copy][bin_index_f32(a.w, m)], 1u);
        atomicAdd(&lh[copy][bin_index_f32(b.x, m)], 1u);
        atomicAdd(&lh[copy][bin_index_f32(b.y, m)], 1u);
        atomicAdd(&lh[copy][bin_index_f32(b.z, m)], 1u);
        atomicAdd(&lh[copy][bin_index_f32(b.w, m)], 1u);
    }
    if (blockIdx.x == 0 && threadIdx.x < (int)(nper & 7)) {
        atomicAdd(&lh[copy][bin_index_f32(xc[nv2 * 8 + threadIdx.x], m)], 1u);
    }
    __syncthreads();
    for (int i = threadIdx.x; i < BINS; i += 256) {
        u32 s = 0;
#pragma unroll
        for (int k = 0; k < 8; ++k) s += lh[k][i];
        if (s) atomicAdd(&h256[c * BINS + i], s);
    }
}

// ---------------- output: fused mask-table (per-block LDS) + out = x * mask[idx] ----------------

__global__ __launch_bounds__(256) void k_output(const float* __restrict__ x, const float* __restrict__ mv,
                                                const float* __restrict__ hist_in, const float* __restrict__ logp_ref,
                                                const u32* __restrict__ h256, float* __restrict__ out, i64 nper) {
    __shared__ double smv_s[BINS];
    __shared__ double maskl[BINS];
    __shared__ double stot;
    const int c = blockIdx.y;
    const int b = threadIdx.x;
    // EMA with separately-rounded f32 ops, matching numpy ufunc-by-ufunc rounding
    float h = hist_in[c * BINS + b];
    float nn = (float)h256[c * BINS + b];
    float t = __fadd_rn(__fmul_rn(0.98f, h), __fmul_rn(0.02f, nn));
    float smf = __fadd_rn(t, 1e-8f);
    double sm = (double)smf;
    smv_s[b] = sm;
    __syncthreads();
    if (b < 64) {
        double s = smv_s[b] + smv_s[b + 64] + smv_s[b + 128] + smv_s[b + 192];
        for (int o = 32; o; o >>= 1) s += __shfl_down(s, o);
        if (b == 0) stot = s;
    }
    __syncthreads();
    double Lam = (double)logp_ref[c * BINS + b] - log(sm / stot);
    maskl[b] = 1.0 / (1.0 + exp(Lam + 2.0));   // sigmoid(-(Lam - THRESH)), THRESH = -2
    __syncthreads();

    const float m = mv[c];
    const float* xc = x + (i64)c * nper;
    float* oc = out + (i64)c * nper;
    const i64 nv2 = nper >> 3;
    const float4* xv = (const float4*)xc;
    float4* ov = (float4*)oc;
    for (i64 i = (i64)blockIdx.x * 256 + threadIdx.x; i < nv2; i += (i64)gridDim.x * 256) {
        float4 a = xv[2 * i], bb = xv[2 * i + 1];
        float4 oa, ob;
        oa.x = (float)((double)a.x * maskl[bin_index_f32(a.x, m)]);
        oa.y = (float)((double)a.y * maskl[bin_index_f32(a.y, m)]);
        oa.z = (float)((double)a.z * maskl[bin_index_f32(a.z, m)]);
        oa.w = (float)((double)a.w * maskl[bin_index_f32(a.w, m)]);
        ob.x = (float)((double)bb.x * maskl[bin_index_f32(bb.x, m)]);
        ob.y = (float)((double)bb.y * maskl[bin_index_f32(bb.y, m)]);
        ob.z = (float)((double)bb.z * maskl[bin_index_f32(bb.z, m)]);
        ob.w = (float)((double)bb.w * maskl[bin_index_f32(bb.w, m)]);
        ov[2 * i] = oa;
        ov[2 * i + 1] = ob;
    }
    if (blockIdx.x == 0 && threadIdx.x < (int)(nper & 7)) {
        i64 i = nv2 * 8 + threadIdx.x;
        float v = xc[i];
        oc[i] = (float)((double)v * maskl[bin_index_f32(v, m)]);
    }
}

// ---------------- launch ----------------

extern "C" void kernel_launch(void* const* d_in, const int* in_sizes, int n_in,
                              void* d_out, int out_size, void* d_ws, size_t ws_size,
                              hipStream_t stream) {
    const float* x        = (const float*)d_in[0];
    const float* hist_in  = (const float*)d_in[1];
    const float* logp_ref = (const float*)d_in[2];
    float* out = (float*)d_out;

    const int C = in_sizes[1] / BINS;            // 5
    const i64 total = (i64)in_sizes[0];
    const i64 nper = total / C;                  // B*L = 8388608

    // ---- workspace: [zeroed control/hist region][fixed-slot candidate buffer] ----
    char* w = (char*)d_ws;
    size_t off = 0;
    float*  mv   = (float*)(w + off);  off += 4 * ((C + 7) & ~7);
    u32* h256   = (u32*)(w + off); off += 4 * BINS * C;
    u32* oflow  = (u32*)(w + off); off += 4 * C;
    u32* goob   = (u32*)(w + off); off += 4 * C;
    u32* flag   = (u32*)(w + off); off += 4 * C;
    u32* cselA  = (u32*)(w + off); off += 4 * 4 * C;
    u32* gha    = (u32*)(w + off); off += 4 * A_BINS * C;
    u32* g3a    = (u32*)(w + off); off += 4 * B_BINS * C;
    u32* g3b    = (u32*)(w + off); off += 4 * B_BINS * C;
    const size_t zbytes = off;
    off = (off + 255) & ~(size_t)255;
    u32* cand = (u32*)(w + off);
    const i64 ntot = (i64)NBLK * SLOT;                                // entries per channel
    const size_t cand_bytes = (size_t)4 * (size_t)C * (size_t)ntot;   // ~15.7 MB
    const int do_cand = (ws_size >= off + cand_bytes) ? 1 : 0;

    hipMemsetAsync(d_ws, 0, zbytes, stream);

    const double virt = 0.99 * (double)(nper - 1);
    const i64 k0 = (i64)floor(virt);
    const double gamma = virt - (double)k0;
    const u32 needed = (u32)(nper - k0);   // top-count that must be in candidates

    dim3 blk(256);
    dim3 grd(NBLK, (unsigned)C);
    dim3 grd64(64, (unsigned)C);

    k_pass1<<<grd, blk, 0, stream>>>(x, cand, gha, oflow, goob, nper, do_cand);
    if (do_cand) {
        k_cselA_pick<<<(unsigned)C, blk, 0, stream>>>(gha, oflow, goob, flag, cselA, needed);
        k_cselB_hist<<<grd64, blk, 0, stream>>>(cand, flag, cselA, g3a, g3b, ntot);
        k_cselB_pick<<<(unsigned)C, blk, 0, stream>>>(g3a, g3b, flag, cselA, mv, gamma);
    } else {
        k_flag_force<<<1, 64, 0, stream>>>(flag, C);
    }
    // self-contained fallback (1 block per flagged channel; early-exits otherwise)
    k_fallback<<<(unsigned)C, blk, 0, stream>>>(x, flag, mv, nper, (u32)k0, gamma);
    // main path
    k_hist_idx<<<grd, blk, 0, stream>>>(x, mv, h256, nper);
    k_output<<<grd, blk, 0, stream>>>(x, mv, hist_in, logp_ref, h256, out, nper);
}

// Round 9
// 190.496 us; speedup vs baseline: 1.8460x; 1.0229x over previous
//
#include <hip/hip_runtime.h>
#include <math.h>

typedef unsigned int u32;
typedef unsigned long long u64;
typedef long long i64;
typedef float float4n __attribute__((ext_vector_type(4)));   // native vec for nontemporal builtins

#define BINS 256
#define TBITS 0x40000000u    /* bit pattern of 2.0f : compaction threshold          */
#define A_BASE 131072u       /* TBITS >> 13                                         */
#define A_BINS 4096          /* covers |x| in [2, 32)                               */
#define B_BINS 8192          /* low 13 bits                                         */
#define SLOT 1152            /* per-block candidate slot (mean ~745, +15 sigma)     */
#define NBLK 512             /* blocks per channel for full passes                  */

// ---------------- helpers ----------------

// Bit-exact replica of the float32 numpy pipeline:
//   idx = trunc(min(|x|/mv, 1.0f) * 255.0f)   (*8 and /8 are exact pow2 ops)
__device__ __forceinline__ int bin_index_f32(float xv, float mv) {
    float r = __fdiv_rn(fabsf(xv), mv);
    r = fminf(r, 1.0f);
    return (int)__fmul_rn(r, 255.0f);
}

// Parallel rank-select over h[0..256*PER) for `target`; one thread writes
// res[0]=bucket, res[1]=target-cum_excl(bucket). Caller zeroes res, syncs after.
template<int PER>
__device__ void block_select(const u32* __restrict__ h, u32 target,
                             u32* ssum, u32* res) {
    const int t = threadIdx.x;
    u32 loc[PER];
    u32 s = 0;
    const int base = t * PER;
#pragma unroll
    for (int j = 0; j < PER; ++j) { loc[j] = h[base + j]; s += loc[j]; }
    ssum[t] = s;
    __syncthreads();
    for (int off = 1; off < 256; off <<= 1) {
        u32 add = (t >= off) ? ssum[t - off] : 0;
        __syncthreads();
        ssum[t] += add;
        __syncthreads();
    }
    u32 cum = ssum[t] - s;
#pragma unroll
    for (int j = 0; j < PER; ++j) {
        u32 cnt = loc[j];
        if (target >= cum && target < cum + cnt) { res[0] = (u32)(base + j); res[1] = target - cum; }
        cum += cnt;
    }
    __syncthreads();
}

// numpy float32 _lerp between exact order stats v0bits <= v1bits
__device__ __forceinline__ float np_lerp_f32(u32 v0bits, u32 v1bits, double gamma) {
    float v0 = __uint_as_float(v0bits);
    float v1 = __uint_as_float(v1bits);
    float dba = __fsub_rn(v1, v0);
    float q;
    if (gamma >= 0.5) q = __fsub_rn(v1, __fmul_rn(dba, (float)(1.0 - gamma)));
    else              q = __fadd_rn(v0, __fmul_rn(dba, (float)gamma));
    return fmaxf(q, 1e-8f);
}

// ---------------- pass 1: streaming threshold-compaction + fused 4096-bin candidate hist ----------------

__global__ __launch_bounds__(256) void k_pass1(const float* __restrict__ x, u32* __restrict__ cand,
                                               u32* __restrict__ gha, u32* __restrict__ oflow,
                                               u32* __restrict__ goob, i64 nper, int do_cand) {
    __shared__ u32 lbuf[SLOT];
    __shared__ u32 lha[A_BINS];
    __shared__ u32 lcnt, loob;
    const int c = blockIdx.y;
    for (int i = threadIdx.x; i < A_BINS; i += 256) lha[i] = 0;
    if (threadIdx.x == 0) { lcnt = 0; loob = 0; }
    __syncthreads();
    const float* xc = x + (i64)c * nper;
    const i64 nv = nper >> 2;
    const float4* xv = (const float4*)xc;
    for (i64 i = (i64)blockIdx.x * 256 + threadIdx.x; i < nv; i += (i64)gridDim.x * 256) {
        float4 v = xv[i];
        u32 b;
        b = __float_as_uint(fabsf(v.x));
        if (b >= TBITS) { u32 p = atomicAdd(&lcnt, 1u); if (p < SLOT) lbuf[p] = b;
                          u32 bin = (b >> 13) - A_BASE; if (bin >= A_BINS) { atomicAdd(&loob, 1u); bin = A_BINS - 1; }
                          atomicAdd(&lha[bin], 1u); }
        b = __float_as_uint(fabsf(v.y));
        if (b >= TBITS) { u32 p = atomicAdd(&lcnt, 1u); if (p < SLOT) lbuf[p] = b;
                          u32 bin = (b >> 13) - A_BASE; if (bin >= A_BINS) { atomicAdd(&loob, 1u); bin = A_BINS - 1; }
                          atomicAdd(&lha[bin], 1u); }
        b = __float_as_uint(fabsf(v.z));
        if (b >= TBITS) { u32 p = atomicAdd(&lcnt, 1u); if (p < SLOT) lbuf[p] = b;
                          u32 bin = (b >> 13) - A_BASE; if (bin >= A_BINS) { atomicAdd(&loob, 1u); bin = A_BINS - 1; }
                          atomicAdd(&lha[bin], 1u); }
        b = __float_as_uint(fabsf(v.w));
        if (b >= TBITS) { u32 p = atomicAdd(&lcnt, 1u); if (p < SLOT) lbuf[p] = b;
                          u32 bin = (b >> 13) - A_BASE; if (bin >= A_BINS) { atomicAdd(&loob, 1u); bin = A_BINS - 1; }
                          atomicAdd(&lha[bin], 1u); }
    }
    if (blockIdx.x == 0 && threadIdx.x < (int)(nper & 3)) {
        u32 b = __float_as_uint(fabsf(xc[nv * 4 + threadIdx.x]));
        if (b >= TBITS) { u32 p = atomicAdd(&lcnt, 1u); if (p < SLOT) lbuf[p] = b;
                          u32 bin = (b >> 13) - A_BASE; if (bin >= A_BINS) { atomicAdd(&loob, 1u); bin = A_BINS - 1; }
                          atomicAdd(&lha[bin], 1u); }
    }
    __syncthreads();
    for (int i = threadIdx.x; i < A_BINS; i += 256)
        if (lha[i]) atomicAdd(&gha[c * A_BINS + i], lha[i]);
    if (threadIdx.x == 0) {
        if (loob) atomicExch(&goob[c], 1u);
        if (lcnt > SLOT) { atomicExch(&oflow[c], 1u); lcnt = SLOT; }
    }
    __syncthreads();
    if (do_cand) {
        const u32 cnt = lcnt;
        u32* slot = cand + ((i64)c * gridDim.x + blockIdx.x) * SLOT;
        for (u32 j = threadIdx.x; j < SLOT; j += 256)
            slot[j] = (j < cnt) ? lbuf[j] : 0u;   // pad = 0, below every candidate
    }
}

// ---------------- stage B hist, with per-block redundant A-pick (deterministic) ----------------

__global__ __launch_bounds__(256) void k_cselB_hist(const u32* __restrict__ cand, const u32* __restrict__ gha,
                                                    const u32* __restrict__ oflow, const u32* __restrict__ goob,
                                                    u32* __restrict__ flag, u32* __restrict__ cselA,
                                                    u32* __restrict__ g3a, u32* __restrict__ g3b,
                                                    i64 ntot, u32 needed) {
    __shared__ u32 la[B_BINS], lb[B_BINS];
    __shared__ u32 ssum[256];
    __shared__ u32 prA[4];
    __shared__ u32 s_total;
    const int c = blockIdx.y;
    const int t = threadIdx.x;
    // A-pick: every block computes it from gha (identical input -> identical result)
    if (t < 4) prA[t] = 0;
    const u32* h = gha + c * A_BINS;
    u32 loc[16];
    u32 s = 0;
    const int base = t * 16;
#pragma unroll
    for (int j = 0; j < 16; ++j) { loc[j] = h[base + j]; s += loc[j]; }
    ssum[t] = s;
    __syncthreads();
    for (int off = 1; off < 256; off <<= 1) {
        u32 add = (t >= off) ? ssum[t - off] : 0;
        __syncthreads();
        ssum[t] += add;
        __syncthreads();
    }
    if (t == 255) s_total = ssum[255];
    __syncthreads();
    const u32 total = s_total;
    const u32 bad = (oflow[c] != 0) || (goob[c] != 0) || (total < needed) || (needed < 2);
    if (bad) {
        if (blockIdx.x == 0 && t == 0) flag[c] = 1u;
        return;
    }
    const u32 t0 = total - needed;
    const u32 t1 = t0 + 1;
    u32 cum = ssum[t] - s;
#pragma unroll
    for (int j = 0; j < 16; ++j) {
        u32 cnt = loc[j];
        if (t0 >= cum && t0 < cum + cnt) { prA[0] = (u32)(base + j); prA[1] = t0 - cum; }
        if (t1 >= cum && t1 < cum + cnt) { prA[2] = (u32)(base + j); prA[3] = t1 - cum; }
        cum += cnt;
    }
    __syncthreads();
    const u32 topA0 = A_BASE + prA[0];
    const u32 topA1 = A_BASE + prA[2];
    if (blockIdx.x == 0 && t == 0) {
        flag[c] = 0u;
        cselA[c * 4 + 0] = prA[0]; cselA[c * 4 + 1] = prA[1];
        cselA[c * 4 + 2] = prA[2]; cselA[c * 4 + 3] = prA[3];
    }
    // B-level histogram of the two selected A-buckets
    for (int i = t; i < B_BINS; i += 256) { la[i] = 0; lb[i] = 0; }
    __syncthreads();
    const uint4* cd = (const uint4*)(cand + (i64)c * ntot);
    const i64 nv4 = ntot >> 2;
    for (i64 i = (i64)blockIdx.x * 256 + t; i < nv4; i += (i64)gridDim.x * 256) {
        uint4 v = cd[i];
        u32 b;
        b = v.x;
        if (b >= TBITS) { u32 tb = b >> 13; if (tb == topA0) atomicAdd(&la[b & (B_BINS - 1)], 1u); if (tb == topA1) atomicAdd(&lb[b & (B_BINS - 1)], 1u); }
        b = v.y;
        if (b >= TBITS) { u32 tb = b >> 13; if (tb == topA0) atomicAdd(&la[b & (B_BINS - 1)], 1u); if (tb == topA1) atomicAdd(&lb[b & (B_BINS - 1)], 1u); }
        b = v.z;
        if (b >= TBITS) { u32 tb = b >> 13; if (tb == topA0) atomicAdd(&la[b & (B_BINS - 1)], 1u); if (tb == topA1) atomicAdd(&lb[b & (B_BINS - 1)], 1u); }
        b = v.w;
        if (b >= TBITS) { u32 tb = b >> 13; if (tb == topA0) atomicAdd(&la[b & (B_BINS - 1)], 1u); if (tb == topA1) atomicAdd(&lb[b & (B_BINS - 1)], 1u); }
    }
    __syncthreads();
    for (int i = t; i < B_BINS; i += 256) {
        if (la[i]) atomicAdd(&g3a[c * B_BINS + i], la[i]);
        if (lb[i]) atomicAdd(&g3b[c * B_BINS + i], lb[i]);
    }
}

__global__ void k_flag_force(u32* __restrict__ flag, int C) {
    if (threadIdx.x < C) flag[threadIdx.x] = 1u;
}

// ---------------- mv finalize: B-pick + lerp, OR self-contained exact fallback ----------------

__global__ __launch_bounds__(256) void k_mv_final(const float* __restrict__ x, const u32* __restrict__ flag,
                                                  const u32* __restrict__ cselA,
                                                  const u32* __restrict__ g3a, const u32* __restrict__ g3b,
                                                  float* __restrict__ mv, i64 nper, u32 k0, double gamma) {
    __shared__ u32 h0[2048], h1[2048];
    __shared__ u32 ssum[256];
    __shared__ u32 pr[4];
    __shared__ u32 st[4];
    const int c = blockIdx.x;
    const int t = threadIdx.x;

    if (!flag[c]) {
        if (t < 4) pr[t] = 0;
        __syncthreads();
        block_select<32>(g3a + c * B_BINS, cselA[c * 4 + 1], ssum, &pr[0]);
        block_select<32>(g3b + c * B_BINS, cselA[c * 4 + 3], ssum, &pr[2]);
        if (t == 0) {
            u32 v0bits = ((A_BASE + cselA[c * 4 + 0]) << 13) | pr[0];
            u32 v1bits = ((A_BASE + cselA[c * 4 + 2]) << 13) | pr[2];
            mv[c] = np_lerp_f32(v0bits, v1bits, gamma);
        }
        return;
    }

    // ---- fallback: in-block 3-level exact select over the full channel ----
    const float* xc = x + (i64)c * nper;
    const i64 nv = nper >> 2;
    const int rem = (int)(nper & 3);
    const float4* xv = (const float4*)xc;

    // level 1: bits 31..21 (1024 bins)
    for (int i = t; i < 1024; i += 256) h0[i] = 0;
    __syncthreads();
    for (i64 i = t; i < nv; i += 256) {
        float4 v = xv[i];
        atomicAdd(&h0[__float_as_uint(fabsf(v.x)) >> 21], 1u);
        atomicAdd(&h0[__float_as_uint(fabsf(v.y)) >> 21], 1u);
        atomicAdd(&h0[__float_as_uint(fabsf(v.z)) >> 21], 1u);
        atomicAdd(&h0[__float_as_uint(fabsf(v.w)) >> 21], 1u);
    }
    if (t < rem) atomicAdd(&h0[__float_as_uint(fabsf(xc[nv * 4 + t])) >> 21], 1u);
    __syncthreads();
    if (t < 4) pr[t] = 0;
    __syncthreads();
    block_select<4>(h0, k0, ssum, &pr[0]);
    block_select<4>(h0, k0 + 1, ssum, &pr[2]);
    if (t < 4) st[t] = pr[t];
    __syncthreads();

    // level 2: bits 20..10 (2048 bins, two chains)
    const u32 p0 = st[0], p1 = st[2];
    for (int i = t; i < 2048; i += 256) { h0[i] = 0; h1[i] = 0; }
    __syncthreads();
    for (i64 i = t; i < nv; i += 256) {
        float4 v = xv[i];
        u32 b;
        b = __float_as_uint(fabsf(v.x));
        if ((b >> 21) == p0) atomicAdd(&h0[(b >> 10) & 2047], 1u);
        if ((b >> 21) == p1) atomicAdd(&h1[(b >> 10) & 2047], 1u);
        b = __float_as_uint(fabsf(v.y));
        if ((b >> 21) == p0) atomicAdd(&h0[(b >> 10) & 2047], 1u);
        if ((b >> 21) == p1) atomicAdd(&h1[(b >> 10) & 2047], 1u);
        b = __float_as_uint(fabsf(v.z));
        if ((b >> 21) == p0) atomicAdd(&h0[(b >> 10) & 2047], 1u);
        if ((b >> 21) == p1) atomicAdd(&h1[(b >> 10) & 2047], 1u);
        b = __float_as_uint(fabsf(v.w));
        if ((b >> 21) == p0) atomicAdd(&h0[(b >> 10) & 2047], 1u);
        if ((b >> 21) == p1) atomicAdd(&h1[(b >> 10) & 2047], 1u);
    }
    if (t < rem) {
        u32 b = __float_as_uint(fabsf(xc[nv * 4 + t]));
        if ((b >> 21) == p0) atomicAdd(&h0[(b >> 10) & 2047], 1u);
        if ((b >> 21) == p1) atomicAdd(&h1[(b >> 10) & 2047], 1u);
    }
    __syncthreads();
    if (t < 4) pr[t] = 0;
    __syncthreads();
    block_select<8>(h0, st[1], ssum, &pr[0]);
    block_select<8>(h1, st[3], ssum, &pr[2]);
    if (t == 0) { st[0] = (p0 << 11) | pr[0]; st[1] = pr[1]; st[2] = (p1 << 11) | pr[2]; st[3] = pr[3]; }
    __syncthreads();

    // level 3: bits 9..0 (1024 bins, two chains)
    const u32 q0 = st[0], q1 = st[2];
    for (int i = t; i < 1024; i += 256) { h0[i] = 0; h1[i] = 0; }
    __syncthreads();
    for (i64 i = t; i < nv; i += 256) {
        float4 v = xv[i];
        u32 b;
        b = __float_as_uint(fabsf(v.x));
        if ((b >> 10) == q0) atomicAdd(&h0[b & 1023], 1u);
        if ((b >> 10) == q1) atomicAdd(&h1[b & 1023], 1u);
        b = __float_as_uint(fabsf(v.y));
        if ((b >> 10) == q0) atomicAdd(&h0[b & 1023], 1u);
        if ((b >> 10) == q1) atomicAdd(&h1[b & 1023], 1u);
        b = __float_as_uint(fabsf(v.z));
        if ((b >> 10) == q0) atomicAdd(&h0[b & 1023], 1u);
        if ((b >> 10) == q1) atomicAdd(&h1[b & 1023], 1u);
        b = __float_as_uint(fabsf(v.w));
        if ((b >> 10) == q0) atomicAdd(&h0[b & 1023], 1u);
        if ((b >> 10) == q1) atomicAdd(&h1[b & 1023], 1u);
    }
    if (t < rem) {
        u32 b = __float_as_uint(fabsf(xc[nv * 4 + t]));
        if ((b >> 10) == q0) atomicAdd(&h0[b & 1023], 1u);
        if ((b >> 10) == q1) atomicAdd(&h1[b & 1023], 1u);
    }
    __syncthreads();
    if (t < 4) pr[t] = 0;
    __syncthreads();
    block_select<4>(h0, st[1], ssum, &pr[0]);
    block_select<4>(h1, st[3], ssum, &pr[2]);
    if (t == 0) {
        u32 v0bits = (q0 << 10) | pr[0];
        u32 v1bits = (q1 << 10) | pr[2];
        mv[c] = np_lerp_f32(v0bits, v1bits, gamma);
    }
}

// ---------------- 256-bin index histogram (round-3 verbatim, single-float4 coalesced) ----------------

__global__ __launch_bounds__(256) void k_hist_idx(const float* __restrict__ x, const float* __restrict__ mv,
                                                  u32* __restrict__ h256, i64 nper) {
    __shared__ u32 lh[8][257];
    const int c = blockIdx.y;
    const float m = mv[c];
    for (int i = threadIdx.x; i < 8 * 257; i += 256) (&lh[0][0])[i] = 0;
    __syncthreads();
    const float* xc = x + (i64)c * nper;
    const i64 nv = nper >> 2;
    const int copy = threadIdx.x & 7;
    const float4* xv = (const float4*)xc;
    for (i64 i = (i64)blockIdx.x * 256 + threadIdx.x; i < nv; i += (i64)gridDim.x * 256) {
        float4 v = xv[i];
        atomicAdd(&lh[copy][bin_index_f32(v.x, m)], 1u);
        atomicAdd(&lh[copy][bin_index_f32(v.y, m)], 1u);
        atomicAdd(&lh[copy][bin_index_f32(v.z, m)], 1u);
        atomicAdd(&lh[copy][bin_index_f32(v.w, m)], 1u);
    }
    if (blockIdx.x == 0 && threadIdx.x < (int)(nper & 3)) {
        atomicAdd(&lh[copy][bin_index_f32(xc[nv * 4 + threadIdx.x], m)], 1u);
    }
    __syncthreads();
    for (int i = threadIdx.x; i < BINS; i += 256) {
        u32 s = 0;
#pragma unroll
        for (int k = 0; k < 8; ++k) s += lh[k][i];
        if (s) atomicAdd(&h256[c * BINS + i], s);
    }
}

// ---------------- output: fused mask-table + out = x * mask[idx], nontemporal stores ----------------

__global__ __launch_bounds__(256) void k_output(const float* __restrict__ x, const float* __restrict__ mv,
                                                const float* __restrict__ hist_in, const float* __restrict__ logp_ref,
                                                const u32* __restrict__ h256, float* __restrict__ out, i64 nper) {
    __shared__ double smv_s[BINS];
    __shared__ double maskl[BINS];
    __shared__ double stot;
    const int c = blockIdx.y;
    const int b = threadIdx.x;
    // EMA with separately-rounded f32 ops, matching numpy ufunc-by-ufunc rounding
    float h = hist_in[c * BINS + b];
    float nn = (float)h256[c * BINS + b];
    float t = __fadd_rn(__fmul_rn(0.98f, h), __fmul_rn(0.02f, nn));
    float smf = __fadd_rn(t, 1e-8f);
    double sm = (double)smf;
    smv_s[b] = sm;
    __syncthreads();
    if (b < 64) {
        double s = smv_s[b] + smv_s[b + 64] + smv_s[b + 128] + smv_s[b + 192];
        for (int o = 32; o; o >>= 1) s += __shfl_down(s, o);
        if (b == 0) stot = s;
    }
    __syncthreads();
    double Lam = (double)logp_ref[c * BINS + b] - log(sm / stot);
    maskl[b] = 1.0 / (1.0 + exp(Lam + 2.0));   // sigmoid(-(Lam - THRESH)), THRESH = -2
    __syncthreads();

    const float m = mv[c];
    const float* xc = x + (i64)c * nper;
    float* oc = out + (i64)c * nper;
    const i64 nv = nper >> 2;
    const float4* xv = (const float4*)xc;
    float4n* ov = (float4n*)oc;
    for (i64 i = (i64)blockIdx.x * 256 + threadIdx.x; i < nv; i += (i64)gridDim.x * 256) {
        float4 v = xv[i];
        float4n o;
        o.x = (float)((double)v.x * maskl[bin_index_f32(v.x, m)]);
        o.y = (float)((double)v.y * maskl[bin_index_f32(v.y, m)]);
        o.z = (float)((double)v.z * maskl[bin_index_f32(v.z, m)]);
        o.w = (float)((double)v.w * maskl[bin_index_f32(v.w, m)]);
        __builtin_nontemporal_store(o, &ov[i]);   // keep x L3-resident during the write stream
    }
    if (blockIdx.x == 0 && threadIdx.x < (int)(nper & 3)) {
        i64 i = nv * 4 + threadIdx.x;
        float v = xc[i];
        oc[i] = (float)((double)v * maskl[bin_index_f32(v, m)]);
    }
}

// ---------------- launch ----------------

extern "C" void kernel_launch(void* const* d_in, const int* in_sizes, int n_in,
                              void* d_out, int out_size, void* d_ws, size_t ws_size,
                              hipStream_t stream) {
    const float* x        = (const float*)d_in[0];
    const float* hist_in  = (const float*)d_in[1];
    const float* logp_ref = (const float*)d_in[2];
    float* out = (float*)d_out;

    const int C = in_sizes[1] / BINS;            // 5
    const i64 total = (i64)in_sizes[0];
    const i64 nper = total / C;                  // B*L = 8388608

    // ---- workspace: [zeroed control/hist region][fixed-slot candidate buffer] ----
    char* w = (char*)d_ws;
    size_t off = 0;
    float* mv   = (float*)(w + off); off += 4 * ((C + 7) & ~7);
    u32* h256   = (u32*)(w + off); off += 4 * BINS * C;
    u32* oflow  = (u32*)(w + off); off += 4 * C;
    u32* goob   = (u32*)(w + off); off += 4 * C;
    u32* flag   = (u32*)(w + off); off += 4 * C;
    u32* cselA  = (u32*)(w + off); off += 4 * 4 * C;
    u32* gha    = (u32*)(w + off); off += 4 * A_BINS * C;
    u32* g3a    = (u32*)(w + off); off += 4 * B_BINS * C;
    u32* g3b    = (u32*)(w + off); off += 4 * B_BINS * C;
    const size_t zbytes = off;
    off = (off + 255) & ~(size_t)255;
    u32* cand = (u32*)(w + off);
    const i64 ntot = (i64)NBLK * SLOT;                                // entries per channel
    const size_t cand_bytes = (size_t)4 * (size_t)C * (size_t)ntot;   // ~11.8 MB
    const int do_cand = (ws_size >= off + cand_bytes) ? 1 : 0;

    (void)hipMemsetAsync(d_ws, 0, zbytes, stream);

    const double virt = 0.99 * (double)(nper - 1);
    const i64 k0 = (i64)floor(virt);
    const double gamma = virt - (double)k0;
    const u32 needed = (u32)(nper - k0);   // top-count that must be in candidates

    dim3 blk(256);
    dim3 grd(NBLK, (unsigned)C);
    dim3 grd64(64, (unsigned)C);

    k_pass1<<<grd, blk, 0, stream>>>(x, cand, gha, oflow, goob, nper, do_cand);
    if (do_cand) {
        k_cselB_hist<<<grd64, blk, 0, stream>>>(cand, gha, oflow, goob, flag, cselA, g3a, g3b, ntot, needed);
    } else {
        k_flag_force<<<1, 64, 0, stream>>>(flag, C);
    }
    k_mv_final<<<(unsigned)C, blk, 0, stream>>>(x, flag, cselA, g3a, g3b, mv, nper, (u32)k0, gamma);
    k_hist_idx<<<grd, blk, 0, stream>>>(x, mv, h256, nper);
    k_output<<<grd, blk, 0, stream>>>(x, mv, hist_in, logp_ref, h256, out, nper);
}